// Round 9
// baseline (479.530 us; speedup 1.0000x reference)
//
#include <hip/hip_runtime.h>
#include <hip/hip_bf16.h>
#include <math.h>

#define N_LIGC 1024
#define NTOT 9216
#define KNN 48
#define HID 256
#define DEPTHC 5
#define ETOT (N_LIGC*KNN)
#define KBINS 4096
#define PACK_BLKS 1484

typedef unsigned short u16;
typedef __attribute__((ext_vector_type(8))) short bf16x8;
typedef __attribute__((ext_vector_type(4))) float f32x4;

__device__ __forceinline__ float freq_f(int i){
  double p = (double)(1 << (2*i));
  return (float)((2.0*3.14159265358979323846)*p/15.0);
}
// fast silu/sigmoid: native exp + single v_rcp_f32 (avoids IEEE div sequence)
__device__ __forceinline__ float silu_f(float v){
  return v*__builtin_amdgcn_rcpf(1.0f+__expf(-v));
}
__device__ __forceinline__ float sigm_f(float v){
  return __builtin_amdgcn_rcpf(1.0f+__expf(-v));
}
// branchless RNE float->bf16
__device__ __forceinline__ u16 f2b(float f){
  unsigned int u = __float_as_uint(f);
  return (u16)((u + 0x7fffu + ((u>>16)&1u)) >> 16);
}
__device__ __forceinline__ float b2f(u16 u){
  union { unsigned int i; float f; } c; c.i = ((unsigned int)u)<<16; return c.f;
}
// precise RNE (for weight packing, matches __float2bfloat16)
__device__ __forceinline__ u16 f2b_p(float f){
  union { __hip_bfloat16 h; u16 u; } c; c.h = __float2bfloat16(f); return c.u;
}

// ---- pack fp32 [L][srcK][N] rows [kOff,kOff+Keff) -> bf16 B-frag layout
__device__ __forceinline__ void pack_one(const float* __restrict__ src,
    u16* __restrict__ dst, int srcK, int kOff, int Keff, int Kp, int N, int idx)
{
  int lane = idx & 63;
  int rest = idx >> 6;
  int Nt = N >> 4;
  int n0 = rest % Nt;
  int rest2 = rest / Nt;
  int Kt = Kp >> 5;
  int k0 = rest2 % Kt;
  int layer = rest2 / Kt;
  int kq = lane >> 4, nl = lane & 15;
  int kb = k0*32 + kq*8, n = n0*16 + nl;
  u16 o[8];
  #pragma unroll
  for (int j=0;j<8;j++){
    int k = kb + j;
    float v = (k < Keff) ? src[((size_t)layer*srcK + kOff + k)*N + n] : 0.f;
    o[j] = f2b_p(v);
  }
  *(uint4*)(dst + (size_t)idx*8) = *(uint4*)o;
}

// ---- merged: weight pack (blocks 0..1483) + embed/h-init (blocks 1484..) ----
__global__ __launch_bounds__(256) void k_prep(
    const float* eW1, const float* eW2, const float* nW1, const float* nW2,
    const float* cW1, const float* cW2, const float* Wout,
    u16* eW1abP, u16* eW1cP, u16* eW2p, u16* nW1p, u16* nW2p,
    u16* cW1abP, u16* cW1cP, u16* cW2p, u16* WoutP,
    const float* __restrict__ protPos, const int* __restrict__ protEle,
    const int* __restrict__ protAA, const int* __restrict__ protBB,
    const float* __restrict__ XtPos, const float* __restrict__ XtFeat,
    const int* __restrict__ tArr, const float* __restrict__ WtTime,
    const float* __restrict__ Wele, const float* __restrict__ Waa,
    const float* __restrict__ Wbb,
    const float* __restrict__ Win, const float* __restrict__ bin,
    float* __restrict__ X0, float* __restrict__ X1,
    float* __restrict__ h, u16* __restrict__ h_bf)
{
  __shared__ float sF[8*40];
  if (blockIdx.x < PACK_BLKS){
    int idx = blockIdx.x*256 + threadIdx.x;
    if (idx < 81920){ pack_one(eW1, eW1abP, 536, 0,   512, 512, 256, idx); return; } idx -= 81920;
    if (idx < 5120 ){ pack_one(eW1, eW1cP,  536, 512, 24,  32,  256, idx); return; } idx -= 5120;
    if (idx < 40960){ pack_one(eW2, eW2p,   256, 0,   256, 256, 256, idx); return; } idx -= 40960;
    if (idx < 81920){ pack_one(nW1, nW1p,   512, 0,   512, 512, 256, idx); return; } idx -= 81920;
    if (idx < 40960){ pack_one(nW2, nW2p,   256, 0,   256, 256, 256, idx); return; } idx -= 40960;
    if (idx < 81920){ pack_one(cW1, cW1abP, 536, 0,   512, 512, 256, idx); return; } idx -= 81920;
    if (idx < 5120 ){ pack_one(cW1, cW1cP,  536, 512, 24,  32,  256, idx); return; } idx -= 5120;
    if (idx < 40960){ pack_one(cW2, cW2p,   256, 0,   256, 256, 256, idx); return; } idx -= 40960;
    if (idx < 1024 ){ pack_one(Wout, WoutP, 256, 0,   256, 256, 32,  idx); return; }
    return;
  }
  int blk=blockIdx.x - PACK_BLKS, tid=threadIdx.x;
  int n0=blk*8;
  for (int x=tid; x<344; x+=256){
    if (x < 320){
      int n = x/40, k = x%40;
      int node = n0+n;
      float v;
      if (node < N_LIGC){
        if (k < 32) v = XtFeat[node*32+k];
        else        v = WtTime[tArr[node]*8 + (k-32)];
      } else {
        int p = node - N_LIGC;
        if (k < 16)      v = Wele[protEle[p]*16 + k];
        else if (k < 32) v = Waa[protAA[p]*16 + (k-16)];
        else             v = Wbb[protBB[p]*8 + (k-32)];
      }
      sF[n*40+k] = v;
    } else {
      int r = x-320; int n = r/3, c = r%3;
      int node = n0+n;
      float v = (node < N_LIGC) ? XtPos[node*3+c] : protPos[(node-N_LIGC)*3+c];
      X0[node*3+c] = v; X1[node*3+c] = v;
    }
  }
  __syncthreads();
  float acc[8];
  float b=bin[tid];
  #pragma unroll
  for (int n=0;n<8;n++) acc[n]=b;
  for (int k=0;k<40;k++){
    float w=Win[k*HID+tid];
    #pragma unroll
    for (int n=0;n<8;n++) acc[n]+=sF[n*40+k]*w;
  }
  #pragma unroll
  for (int n=0;n<8;n++){
    h[(size_t)(n0+n)*HID+tid]=acc[n];
    h_bf[(size_t)(n0+n)*HID+tid]=f2b_p(acc[n]);
  }
}

// ---- KNN: exact top-K via per-thread-minima radix bound + rank-by-count ----
__global__ __launch_bounds__(256) void k_knn(const float* __restrict__ X,
    int* __restrict__ col, u16* __restrict__ emb0)
{
  __shared__ unsigned int hist[KBINS];
  __shared__ unsigned int scanb[256];
  __shared__ float selD[KNN];
  __shared__ int   candI[1024];
  __shared__ float candV[1024];
  __shared__ int sB, sCbase, sChunk, sNcand;
  int b = blockIdx.x, tid = threadIdx.x;
  for (int i=tid;i<KBINS;i+=256) hist[i]=0u;
  if (tid==0){ sNcand=0; }
  float px = X[b*3+0], py = X[b*3+1], pz = X[b*3+2];
  __syncthreads();
  float d2v[36];
  float mn = INFINITY;
  #pragma unroll
  for (int j=0;j<36;j++){
    int i = tid + 256*j;
    float dx = __fsub_rn(px, X[i*3+0]);
    float dy = __fsub_rn(py, X[i*3+1]);
    float dz = __fsub_rn(pz, X[i*3+2]);
    float d2 = __fadd_rn(__fadd_rn(__fmul_rn(dx,dx),__fmul_rn(dy,dy)),__fmul_rn(dz,dz));
    if (i==b) d2 = INFINITY;
    d2v[j] = d2;
    mn = fminf(mn, d2);
  }
  {
    unsigned mkey = __float_as_uint(mn) >> 19;
    if (mkey >= KBINS) mkey = KBINS-1;
    atomicAdd(&hist[mkey], 1u);
  }
  __syncthreads();
  unsigned s=0;
  {
    #pragma unroll 4
    for (int k=0;k<16;k++) s += hist[tid*16+k];
    scanb[tid]=s;
  }
  __syncthreads();
  #pragma unroll
  for (int off=1; off<256; off<<=1){
    unsigned v = (tid>=off) ? scanb[tid-off] : 0u;
    __syncthreads();
    scanb[tid] += v;
    __syncthreads();
  }
  {
    unsigned incl = scanb[tid];
    unsigned excl = incl - s;
    if (excl < (unsigned)KNN && incl >= (unsigned)KNN){ sChunk = tid; sCbase = (int)excl; }
  }
  __syncthreads();
  if (tid==0){
    unsigned c = (unsigned)sCbase; int bin = sChunk*16;
    for (;;bin++){
      unsigned hh = hist[bin];
      if (c + hh >= (unsigned)KNN) break;
      c += hh;
    }
    sB = bin;
  }
  __syncthreads();
  int Bp = sB;
  #pragma unroll
  for (int j=0;j<36;j++){
    float d2 = d2v[j];
    int key = (int)(__float_as_uint(d2) >> 19);
    if (key <= Bp){
      int c = atomicAdd(&sNcand, 1);
      if (c < 1024){ candI[c] = tid + 256*j; candV[c] = d2; }
    }
  }
  __syncthreads();
  {
    int m = sNcand; if (m > 1024) m = 1024;
    for (int c = tid; c < m; c += 256){
      float v = candV[c]; int idx = candI[c];
      int rank = 0;
      for (int o = 0; o < m; o++){
        float ov = candV[o];
        if (ov < v || (ov == v && candI[o] < idx)) rank++;
      }
      if (rank < KNN){ col[b*KNN+rank] = idx; selD[rank] = v; }
    }
  }
  __syncthreads();
  if (tid < KNN){
    float d = sqrtf(selD[tid] + 1e-8f);
    int base = (b*KNN+tid)*12;
    #pragma unroll
    for (int i=0;i<6;i++){
      float fr = freq_f(i);
      emb0[base+i]   = f2b_p(sinf(d*fr));
      emb0[base+6+i] = f2b_p(cosf(d*fr));
    }
  }
}

// ---- k_pq: initial Q/R for layer 0 edge stage ----
__global__ __launch_bounds__(512,1) void k_pq(const u16* __restrict__ h_bf,
    const u16* __restrict__ Wab, float* __restrict__ R, u16* __restrict__ Qb, int l)
{
  __shared__ __align__(16) u16 sA[48*264];
  int blk=blockIdx.x, tid=threadIdx.x;
  int lane=tid&63, wv=tid>>6, quad=lane>>4, nl=lane&15;
  int base = blk*36;
  for (int t=tid; t<48*32; t+=512){
    int i=t>>5, q=t&31;
    uint4 v;
    if (i < 36) v = ((const uint4*)(h_bf + (size_t)(base+i)*HID))[q];
    else { v.x=0u; v.y=0u; v.z=0u; v.w=0u; }
    *(uint4*)(sA + i*264 + q*8) = v;
  }
  __syncthreads();
  const u16* Wl = Wab + (size_t)l*512*HID;
  f32x4 zero4 = {0.f,0.f,0.f,0.f};
  f32x4 aQ[3][2];
  #pragma unroll
  for (int i=0;i<3;i++){ aQ[i][0]=zero4; aQ[i][1]=zero4; }
  #pragma unroll 2
  for (int k0=0;k0<8;k0++){
    bf16x8 a0 = *(const bf16x8*)(sA + (0*16+nl)*264 + k0*32 + quad*8);
    bf16x8 a1 = *(const bf16x8*)(sA + (1*16+nl)*264 + k0*32 + quad*8);
    bf16x8 a2 = *(const bf16x8*)(sA + (2*16+nl)*264 + k0*32 + quad*8);
    const u16* wb = Wl + ((size_t)((k0+8)*16 + wv*2)*64 + lane)*8;
    bf16x8 b0 = *(const bf16x8*)(wb);
    bf16x8 b1 = *(const bf16x8*)(wb + 512);
    aQ[0][0]=__builtin_amdgcn_mfma_f32_16x16x32_bf16(a0,b0,aQ[0][0],0,0,0);
    aQ[0][1]=__builtin_amdgcn_mfma_f32_16x16x32_bf16(a0,b1,aQ[0][1],0,0,0);
    aQ[1][0]=__builtin_amdgcn_mfma_f32_16x16x32_bf16(a1,b0,aQ[1][0],0,0,0);
    aQ[1][1]=__builtin_amdgcn_mfma_f32_16x16x32_bf16(a1,b1,aQ[1][1],0,0,0);
    aQ[2][0]=__builtin_amdgcn_mfma_f32_16x16x32_bf16(a2,b0,aQ[2][0],0,0,0);
    aQ[2][1]=__builtin_amdgcn_mfma_f32_16x16x32_bf16(a2,b1,aQ[2][1],0,0,0);
  }
  #pragma unroll
  for (int mt=0;mt<3;mt++)
  #pragma unroll
  for (int nt=0;nt<2;nt++){
    int n = wv*32 + nt*16 + nl;
    #pragma unroll
    for (int r=0;r<4;r++){
      int m = mt*16 + quad*4 + r;
      if (m < 36) Qb[(size_t)(base+m)*HID + n] = f2b(aQ[mt][nt][r]);
    }
  }
  if (base < N_LIGC){
    f32x4 aR[3][2];
    #pragma unroll
    for (int i=0;i<3;i++){ aR[i][0]=zero4; aR[i][1]=zero4; }
    #pragma unroll 2
    for (int k0=0;k0<8;k0++){
      bf16x8 a0 = *(const bf16x8*)(sA + (0*16+nl)*264 + k0*32 + quad*8);
      bf16x8 a1 = *(const bf16x8*)(sA + (1*16+nl)*264 + k0*32 + quad*8);
      bf16x8 a2 = *(const bf16x8*)(sA + (2*16+nl)*264 + k0*32 + quad*8);
      const u16* wb = Wl + ((size_t)(k0*16 + wv*2)*64 + lane)*8;
      bf16x8 b0 = *(const bf16x8*)(wb);
      bf16x8 b1 = *(const bf16x8*)(wb + 512);
      aR[0][0]=__builtin_amdgcn_mfma_f32_16x16x32_bf16(a0,b0,aR[0][0],0,0,0);
      aR[0][1]=__builtin_amdgcn_mfma_f32_16x16x32_bf16(a0,b1,aR[0][1],0,0,0);
      aR[1][0]=__builtin_amdgcn_mfma_f32_16x16x32_bf16(a1,b0,aR[1][0],0,0,0);
      aR[1][1]=__builtin_amdgcn_mfma_f32_16x16x32_bf16(a1,b1,aR[1][1],0,0,0);
      aR[2][0]=__builtin_amdgcn_mfma_f32_16x16x32_bf16(a2,b0,aR[2][0],0,0,0);
      aR[2][1]=__builtin_amdgcn_mfma_f32_16x16x32_bf16(a2,b1,aR[2][1],0,0,0);
    }
    #pragma unroll
    for (int mt=0;mt<3;mt++)
    #pragma unroll
    for (int nt=0;nt<2;nt++){
      int n = wv*32 + nt*16 + nl;
      #pragma unroll
      for (int r=0;r<4;r++){
        int m = mt*16 + quad*4 + r;
        int node = base + m;
        if (m < 36 && node < N_LIGC) R[(size_t)node*HID + n] = aR[mt][nt][r];
      }
    }
  }
}

// ---- edge combine (48 edges/block, grid 1024) ----
__global__ __launch_bounds__(256,4) void k_comb_edge(
    const u16* __restrict__ Qb, const float* __restrict__ R,
    const float* __restrict__ xc,
    const int* __restrict__ colIdx, const u16* __restrict__ emb0,
    const u16* __restrict__ W1cP, const float* __restrict__ B1,
    const u16* __restrict__ W2p, const float* __restrict__ B2,
    const float* __restrict__ attW, const float* __restrict__ attB,
    u16* __restrict__ agg_bf, int l)
{
  __shared__ __align__(16) u16 sQ[48*264];   // Q gather, then M1 in place
  __shared__ __align__(16) u16 sEA[48*40];
  __shared__ float sR[256];
  __shared__ int sCol[48];
  __shared__ float sD[48];
  __shared__ float sSig[48];
  __shared__ float sDot[48][4];

  int row = blockIdx.x, tid = threadIdx.x;
  int lane = tid & 63, ng = tid >> 6;
  int quad = lane >> 4, nl = lane & 15;

  if (tid < 48) sCol[tid] = colIdx[(size_t)row*KNN + tid];
  sR[tid] = R[(size_t)row*HID + tid];
  __syncthreads();
  for (int t = tid; t < 48*32; t += 256){
    int e = t >> 5, q = t & 31;
    uint4 v = ((const uint4*)(Qb + (size_t)sCol[e]*HID))[q];
    *(uint4*)(sQ + e*264 + q*8) = v;
  }
  if (tid < 48){
    int cg = sCol[tid];
    float dx = xc[row*3+0]-xc[cg*3+0];
    float dy = xc[row*3+1]-xc[cg*3+1];
    float dz = xc[row*3+2]-xc[cg*3+2];
    float d = sqrtf(dx*dx+dy*dy+dz*dz + 1e-8f);
    sD[tid] = d;
    const unsigned int* ep = (const unsigned int*)(emb0 + ((size_t)row*KNN + tid)*12);
    unsigned int* dd = (unsigned int*)(sEA + tid*40 + 12);
    #pragma unroll
    for (int i=0;i<6;i++) dd[i] = ep[i];
    u16* ea = sEA + tid*40;
    #pragma unroll
    for (int i=24;i<32;i++) ea[i] = 0;
  }
  __syncthreads();
  for (int t=tid; t<288; t+=256){
    int e = t/6, i = t - 6*e;
    float fr = 0.41887903f * (float)(1 << (2*i));
    float x = sD[e]*fr;
    u16* ea = sEA + e*40;
    ea[i]   = f2b(__sinf(x));
    ea[6+i] = f2b(__cosf(x));
  }
  __syncthreads();

  f32x4 zero4 = {0.f,0.f,0.f,0.f};
  f32x4 acc[3][4];
  #pragma unroll
  for (int i=0;i<3;i++){ acc[i][0]=zero4; acc[i][1]=zero4; acc[i][2]=zero4; acc[i][3]=zero4; }
  {
    const u16* Wc = W1cP + (size_t)l*32*HID;
    const u16* wb = Wc + ((size_t)(ng*4)*64 + lane)*8;
    bf16x8 b0 = *(const bf16x8*)(wb);
    bf16x8 b1 = *(const bf16x8*)(wb + 512);
    bf16x8 b2 = *(const bf16x8*)(wb + 1024);
    bf16x8 b3 = *(const bf16x8*)(wb + 1536);
    bf16x8 a0 = *(const bf16x8*)(sEA + (0*16+nl)*40 + quad*8);
    bf16x8 a1 = *(const bf16x8*)(sEA + (1*16+nl)*40 + quad*8);
    bf16x8 a2 = *(const bf16x8*)(sEA + (2*16+nl)*40 + quad*8);
    acc[0][0]=__builtin_amdgcn_mfma_f32_16x16x32_bf16(a0,b0,acc[0][0],0,0,0);
    acc[0][1]=__builtin_amdgcn_mfma_f32_16x16x32_bf16(a0,b1,acc[0][1],0,0,0);
    acc[0][2]=__builtin_amdgcn_mfma_f32_16x16x32_bf16(a0,b2,acc[0][2],0,0,0);
    acc[0][3]=__builtin_amdgcn_mfma_f32_16x16x32_bf16(a0,b3,acc[0][3],0,0,0);
    acc[1][0]=__builtin_amdgcn_mfma_f32_16x16x32_bf16(a1,b0,acc[1][0],0,0,0);
    acc[1][1]=__builtin_amdgcn_mfma_f32_16x16x32_bf16(a1,b1,acc[1][1],0,0,0);
    acc[1][2]=__builtin_amdgcn_mfma_f32_16x16x32_bf16(a1,b2,acc[1][2],0,0,0);
    acc[1][3]=__builtin_amdgcn_mfma_f32_16x16x32_bf16(a1,b3,acc[1][3],0,0,0);
    acc[2][0]=__builtin_amdgcn_mfma_f32_16x16x32_bf16(a2,b0,acc[2][0],0,0,0);
    acc[2][1]=__builtin_amdgcn_mfma_f32_16x16x32_bf16(a2,b1,acc[2][1],0,0,0);
    acc[2][2]=__builtin_amdgcn_mfma_f32_16x16x32_bf16(a2,b2,acc[2][2],0,0,0);
    acc[2][3]=__builtin_amdgcn_mfma_f32_16x16x32_bf16(a2,b3,acc[2][3],0,0,0);
  }
  // in-place M1 epilogue: per-thread RMW ownership; A operand lives in sEA
  #pragma unroll
  for (int mt=0;mt<3;mt++)
  #pragma unroll
  for (int nt=0;nt<4;nt++){
    int n = ng*64 + nt*16 + nl;
    float bb = B1[l*HID + n] + sR[n];
    #pragma unroll
    for (int r=0;r<4;r++){
      int m = mt*16 + quad*4 + r;
      float v = acc[mt][nt][r] + bb + b2f(sQ[m*264 + n]);
      sQ[m*264 + n] = f2b(silu_f(v));
    }
  }
  __syncthreads();

  f32x4 acc2[3][4];
  #pragma unroll
  for (int i=0;i<3;i++){ acc2[i][0]=zero4; acc2[i][1]=zero4; acc2[i][2]=zero4; acc2[i][3]=zero4; }
  const u16* W2 = W2p + (size_t)l*HID*HID;
  #pragma unroll 2
  for (int k0=0;k0<8;k0++){
    bf16x8 a0 = *(const bf16x8*)(sQ + (0*16+nl)*264 + k0*32 + quad*8);
    bf16x8 a1 = *(const bf16x8*)(sQ + (1*16+nl)*264 + k0*32 + quad*8);
    bf16x8 a2 = *(const bf16x8*)(sQ + (2*16+nl)*264 + k0*32 + quad*8);
    const u16* wb = W2 + ((size_t)(k0*16 + ng*4)*64 + lane)*8;
    bf16x8 b0 = *(const bf16x8*)(wb);
    bf16x8 b1 = *(const bf16x8*)(wb + 512);
    bf16x8 b2 = *(const bf16x8*)(wb + 1024);
    bf16x8 b3 = *(const bf16x8*)(wb + 1536);
    acc2[0][0]=__builtin_amdgcn_mfma_f32_16x16x32_bf16(a0,b0,acc2[0][0],0,0,0);
    acc2[0][1]=__builtin_amdgcn_mfma_f32_16x16x32_bf16(a0,b1,acc2[0][1],0,0,0);
    acc2[0][2]=__builtin_amdgcn_mfma_f32_16x16x32_bf16(a0,b2,acc2[0][2],0,0,0);
    acc2[0][3]=__builtin_amdgcn_mfma_f32_16x16x32_bf16(a0,b3,acc2[0][3],0,0,0);
    acc2[1][0]=__builtin_amdgcn_mfma_f32_16x16x32_bf16(a1,b0,acc2[1][0],0,0,0);
    acc2[1][1]=__builtin_amdgcn_mfma_f32_16x16x32_bf16(a1,b1,acc2[1][1],0,0,0);
    acc2[1][2]=__builtin_amdgcn_mfma_f32_16x16x32_bf16(a1,b2,acc2[1][2],0,0,0);
    acc2[1][3]=__builtin_amdgcn_mfma_f32_16x16x32_bf16(a1,b3,acc2[1][3],0,0,0);
    acc2[2][0]=__builtin_amdgcn_mfma_f32_16x16x32_bf16(a2,b0,acc2[2][0],0,0,0);
    acc2[2][1]=__builtin_amdgcn_mfma_f32_16x16x32_bf16(a2,b1,acc2[2][1],0,0,0);
    acc2[2][2]=__builtin_amdgcn_mfma_f32_16x16x32_bf16(a2,b2,acc2[2][2],0,0,0);
    acc2[2][3]=__builtin_amdgcn_mfma_f32_16x16x32_bf16(a2,b3,acc2[2][3],0,0,0);
  }
  // M2 epilogue fully in registers
  float aw[4], bb2[4];
  #pragma unroll
  for (int nt=0;nt<4;nt++){
    int n = ng*64 + nt*16 + nl;
    aw[nt]  = attW[l*HID + n];
    bb2[nt] = B2[l*HID + n];
  }
  float dotp[3][4];
  #pragma unroll
  for (int mt=0;mt<3;mt++){
    #pragma unroll
    for (int r=0;r<4;r++) dotp[mt][r] = 0.f;
    #pragma unroll
    for (int nt=0;nt<4;nt++){
      #pragma unroll
      for (int r=0;r<4;r++){
        float s = silu_f(acc2[mt][nt][r] + bb2[nt]);
        acc2[mt][nt][r] = s;
        dotp[mt][r] += s*aw[nt];
      }
    }
  }
  #pragma unroll
  for (int off=1; off<16; off<<=1){
    #pragma unroll
    for (int mt=0;mt<3;mt++)
    #pragma unroll
    for (int r=0;r<4;r++)
      dotp[mt][r] += __shfl_xor(dotp[mt][r], off);
  }
  if (nl == 0){
    #pragma unroll
    for (int mt=0;mt<3;mt++)
    #pragma unroll
    for (int r=0;r<4;r++)
      sDot[mt*16 + quad*4 + r][ng] = dotp[mt][r];
  }
  __syncthreads();
  if (tid < 48) sSig[tid] = sigm_f(sDot[tid][0]+sDot[tid][1]+sDot[tid][2]+sDot[tid][3] + attB[l]);
  __syncthreads();
  float sgv[3][4];
  #pragma unroll
  for (int mt=0;mt<3;mt++)
  #pragma unroll
  for (int r=0;r<4;r++)
    sgv[mt][r] = sSig[mt*16 + quad*4 + r];
  #pragma unroll
  for (int nt=0;nt<4;nt++){
    float a = 0.f;
    #pragma unroll
    for (int mt=0;mt<3;mt++)
    #pragma unroll
    for (int r=0;r<4;r++)
      a += acc2[mt][nt][r]*sgv[mt][r];
    a += __shfl_xor(a, 16);
    a += __shfl_xor(a, 32);
    if (quad == 0) agg_bf[(size_t)row*HID + ng*64 + nt*16 + nl] = f2b(a*0.2f);
  }
}

// ---- node MLP + residual + QC/RC + QE/RE + final outh ----
// grid 256 (1 block/CU), 512 threads (2 waves/SIMD). Post-residual GEMMs
// FUSED: QC+QE share one A-pass (dual-B, 12 MFMA/k0; QE always computed,
// stored only if doE), RC+RE likewise for lig blocks. Halves A ds_reads,
// doubles outstanding B-loads per phase, 4 serial phases -> 2.
__global__ __launch_bounds__(512,1) void k_node(
    float* __restrict__ h, u16* __restrict__ h_bf,
    const u16* __restrict__ agg_bf,
    const u16* __restrict__ W1p, const float* __restrict__ B1,
    const u16* __restrict__ W2p, const float* __restrict__ B2,
    const u16* __restrict__ cWab, u16* __restrict__ QbC, float* __restrict__ RC,
    const u16* __restrict__ eWabN, u16* __restrict__ QbE, float* __restrict__ RE, int doE,
    const u16* __restrict__ WoutP, const float* __restrict__ bout,
    float* __restrict__ outH, int doOut, int l)
{
  __shared__ __align__(16) u16 sA[48*520];
  __shared__ __align__(16) u16 sU[48*264];
  u16* sH = sA;
  int blk=blockIdx.x, tid=threadIdx.x;
  int lane=tid&63, wv=tid>>6, quad=lane>>4, nl=lane&15;
  int base = blk*36;
  for (int t=tid; t<48*64; t+=512){
    int i=t>>6, q=t&63;
    uint4 v;
    if (i < 36){
      int node = base+i;
      if (q<32) v = ((const uint4*)(h_bf + (size_t)node*HID))[q];
      else if (node < N_LIGC) v = ((const uint4*)(agg_bf + (size_t)node*HID))[q-32];
      else { v.x=0u; v.y=0u; v.z=0u; v.w=0u; }
    } else { v.x=0u; v.y=0u; v.z=0u; v.w=0u; }
    *(uint4*)(sA + i*520 + q*8) = v;
  }
  __syncthreads();
  f32x4 zero4 = {0.f,0.f,0.f,0.f};
  f32x4 acc[3][2];
  #pragma unroll
  for (int i=0;i<3;i++){ acc[i][0]=zero4; acc[i][1]=zero4; }
  const u16* Wp = W1p + (size_t)l*512*HID;
  #pragma unroll 2
  for (int k0=0;k0<16;k0++){
    bf16x8 a0 = *(const bf16x8*)(sA + (0*16+nl)*520 + k0*32 + quad*8);
    bf16x8 a1 = *(const bf16x8*)(sA + (1*16+nl)*520 + k0*32 + quad*8);
    bf16x8 a2 = *(const bf16x8*)(sA + (2*16+nl)*520 + k0*32 + quad*8);
    const u16* wb = Wp + ((size_t)(k0*16 + wv*2)*64 + lane)*8;
    bf16x8 b0 = *(const bf16x8*)(wb);
    bf16x8 b1 = *(const bf16x8*)(wb + 512);
    acc[0][0]=__builtin_amdgcn_mfma_f32_16x16x32_bf16(a0,b0,acc[0][0],0,0,0);
    acc[0][1]=__builtin_amdgcn_mfma_f32_16x16x32_bf16(a0,b1,acc[0][1],0,0,0);
    acc[1][0]=__builtin_amdgcn_mfma_f32_16x16x32_bf16(a1,b0,acc[1][0],0,0,0);
    acc[1][1]=__builtin_amdgcn_mfma_f32_16x16x32_bf16(a1,b1,acc[1][1],0,0,0);
    acc[2][0]=__builtin_amdgcn_mfma_f32_16x16x32_bf16(a2,b0,acc[2][0],0,0,0);
    acc[2][1]=__builtin_amdgcn_mfma_f32_16x16x32_bf16(a2,b1,acc[2][1],0,0,0);
  }
  #pragma unroll
  for (int mt=0;mt<3;mt++)
  #pragma unroll
  for (int nt=0;nt<2;nt++){
    int n = wv*32 + nt*16 + nl;
    float bb = B1[l*HID + n];
    #pragma unroll
    for (int r=0;r<4;r++){
      int m = mt*16 + quad*4 + r;
      sU[m*264 + n] = f2b(silu_f(acc[mt][nt][r] + bb));
    }
  }
  __syncthreads();
  f32x4 acc2[3][2];
  #pragma unroll
  for (int i=0;i<3;i++){ acc2[i][0]=zero4; acc2[i][1]=zero4; }
  const u16* W2 = W2p + (size_t)l*HID*HID;
  #pragma unroll 2
  for (int k0=0;k0<8;k0++){
    bf16x8 a0 = *(const bf16x8*)(sU + (0*16+nl)*264 + k0*32 + quad*8);
    bf16x8 a1 = *(const bf16x8*)(sU + (1*16+nl)*264 + k0*32 + quad*8);
    bf16x8 a2 = *(const bf16x8*)(sU + (2*16+nl)*264 + k0*32 + quad*8);
    const u16* wb = W2 + ((size_t)(k0*16 + wv*2)*64 + lane)*8;
    bf16x8 b0 = *(const bf16x8*)(wb);
    bf16x8 b1 = *(const bf16x8*)(wb + 512);
    acc2[0][0]=__builtin_amdgcn_mfma_f32_16x16x32_bf16(a0,b0,acc2[0][0],0,0,0);
    acc2[0][1]=__builtin_amdgcn_mfma_f32_16x16x32_bf16(a0,b1,acc2[0][1],0,0,0);
    acc2[1][0]=__builtin_amdgcn_mfma_f32_16x16x32_bf16(a1,b0,acc2[1][0],0,0,0);
    acc2[1][1]=__builtin_amdgcn_mfma_f32_16x16x32_bf16(a1,b1,acc2[1][1],0,0,0);
    acc2[2][0]=__builtin_amdgcn_mfma_f32_16x16x32_bf16(a2,b0,acc2[2][0],0,0,0);
    acc2[2][1]=__builtin_amdgcn_mfma_f32_16x16x32_bf16(a2,b1,acc2[2][1],0,0,0);
  }
  #pragma unroll
  for (int mt=0;mt<3;mt++)
  #pragma unroll
  for (int nt=0;nt<2;nt++){
    int n = wv*32 + nt*16 + nl;
    float bb = B2[l*HID + n];
    #pragma unroll
    for (int r=0;r<4;r++){
      int m = mt*16 + quad*4 + r;
      if (m < 36){
        size_t idx = (size_t)(base+m)*HID + n;
        float v = h[idx] + acc2[mt][nt][r] + bb;
        h[idx] = v;
        u16 bv = f2b(v);
        h_bf[idx] = bv;
        sH[m*264 + n] = bv;
      } else {
        sH[m*264 + n] = 0;
      }
    }
  }
  __syncthreads();

  int isLig = (base < N_LIGC);
  const u16* Wl = cWab + (size_t)l*512*HID;
  // ---- fused QC+QE: one A-pass, dual B ----
  {
    f32x4 qc[3][2], qe[3][2];
    #pragma unroll
    for (int i=0;i<3;i++){ qc[i][0]=zero4; qc[i][1]=zero4; qe[i][0]=zero4; qe[i][1]=zero4; }
    #pragma unroll 2
    for (int k0=0;k0<8;k0++){
      bf16x8 a0 = *(const bf16x8*)(sH + (0*16+nl)*264 + k0*32 + quad*8);
      bf16x8 a1 = *(const bf16x8*)(sH + (1*16+nl)*264 + k0*32 + quad*8);
      bf16x8 a2 = *(const bf16x8*)(sH + (2*16+nl)*264 + k0*32 + quad*8);
      const u16* wbC = Wl    + ((size_t)((k0+8)*16 + wv*2)*64 + lane)*8;
      const u16* wbE = eWabN + ((size_t)((k0+8)*16 + wv*2)*64 + lane)*8;
      bf16x8 c0 = *(const bf16x8*)(wbC);
      bf16x8 c1 = *(const bf16x8*)(wbC + 512);
      bf16x8 e0 = *(const bf16x8*)(wbE);
      bf16x8 e1 = *(const bf16x8*)(wbE + 512);
      qc[0][0]=__builtin_amdgcn_mfma_f32_16x16x32_bf16(a0,c0,qc[0][0],0,0,0);
      qc[0][1]=__builtin_amdgcn_mfma_f32_16x16x32_bf16(a0,c1,qc[0][1],0,0,0);
      qc[1][0]=__builtin_amdgcn_mfma_f32_16x16x32_bf16(a1,c0,qc[1][0],0,0,0);
      qc[1][1]=__builtin_amdgcn_mfma_f32_16x16x32_bf16(a1,c1,qc[1][1],0,0,0);
      qc[2][0]=__builtin_amdgcn_mfma_f32_16x16x32_bf16(a2,c0,qc[2][0],0,0,0);
      qc[2][1]=__builtin_amdgcn_mfma_f32_16x16x32_bf16(a2,c1,qc[2][1],0,0,0);
      qe[0][0]=__builtin_amdgcn_mfma_f32_16x16x32_bf16(a0,e0,qe[0][0],0,0,0);
      qe[0][1]=__builtin_amdgcn_mfma_f32_16x16x32_bf16(a0,e1,qe[0][1],0,0,0);
      qe[1][0]=__builtin_amdgcn_mfma_f32_16x16x32_bf16(a1,e0,qe[1][0],0,0,0);
      qe[1][1]=__builtin_amdgcn_mfma_f32_16x16x32_bf16(a1,e1,qe[1][1],0,0,0);
      qe[2][0]=__builtin_amdgcn_mfma_f32_16x16x32_bf16(a2,e0,qe[2][0],0,0,0);
      qe[2][1]=__builtin_amdgcn_mfma_f32_16x16x32_bf16(a2,e1,qe[2][1],0,0,0);
    }
    #pragma unroll
    for (int mt=0;mt<3;mt++)
    #pragma unroll
    for (int nt=0;nt<2;nt++){
      int n = wv*32 + nt*16 + nl;
      #pragma unroll
      for (int r=0;r<4;r++){
        int m = mt*16 + quad*4 + r;
        if (m < 36) QbC[(size_t)(base+m)*HID + n] = f2b(qc[mt][nt][r]);
      }
    }
    if (doE){
      #pragma unroll
      for (int mt=0;mt<3;mt++)
      #pragma unroll
      for (int nt=0;nt<2;nt++){
        int n = wv*32 + nt*16 + nl;
        #pragma unroll
        for (int r=0;r<4;r++){
          int m = mt*16 + quad*4 + r;
          if (m < 36) QbE[(size_t)(base+m)*HID + n] = f2b(qe[mt][nt][r]);
        }
      }
    }
  }
  // ---- fused RC+RE (lig blocks only): one A-pass, dual B ----
  if (isLig){
    f32x4 rc[3][2], re[3][2];
    #pragma unroll
    for (int i=0;i<3;i++){ rc[i][0]=zero4; rc[i][1]=zero4; re[i][0]=zero4; re[i][1]=zero4; }
    #pragma unroll 2
    for (int k0=0;k0<8;k0++){
      bf16x8 a0 = *(const bf16x8*)(sH + (0*16+nl)*264 + k0*32 + quad*8);
      bf16x8 a1 = *(const bf16x8*)(sH + (1*16+nl)*264 + k0*32 + quad*8);
      bf16x8 a2 = *(const bf16x8*)(sH + (2*16+nl)*264 + k0*32 + quad*8);
      const u16* wbC = Wl    + ((size_t)(k0*16 + wv*2)*64 + lane)*8;
      const u16* wbE = eWabN + ((size_t)(k0*16 + wv*2)*64 + lane)*8;
      bf16x8 c0 = *(const bf16x8*)(wbC);
      bf16x8 c1 = *(const bf16x8*)(wbC + 512);
      bf16x8 e0 = *(const bf16x8*)(wbE);
      bf16x8 e1 = *(const bf16x8*)(wbE + 512);
      rc[0][0]=__builtin_amdgcn_mfma_f32_16x16x32_bf16(a0,c0,rc[0][0],0,0,0);
      rc[0][1]=__builtin_amdgcn_mfma_f32_16x16x32_bf16(a0,c1,rc[0][1],0,0,0);
      rc[1][0]=__builtin_amdgcn_mfma_f32_16x16x32_bf16(a1,c0,rc[1][0],0,0,0);
      rc[1][1]=__builtin_amdgcn_mfma_f32_16x16x32_bf16(a1,c1,rc[1][1],0,0,0);
      rc[2][0]=__builtin_amdgcn_mfma_f32_16x16x32_bf16(a2,c0,rc[2][0],0,0,0);
      rc[2][1]=__builtin_amdgcn_mfma_f32_16x16x32_bf16(a2,c1,rc[2][1],0,0,0);
      re[0][0]=__builtin_amdgcn_mfma_f32_16x16x32_bf16(a0,e0,re[0][0],0,0,0);
      re[0][1]=__builtin_amdgcn_mfma_f32_16x16x32_bf16(a0,e1,re[0][1],0,0,0);
      re[1][0]=__builtin_amdgcn_mfma_f32_16x16x32_bf16(a1,e0,re[1][0],0,0,0);
      re[1][1]=__builtin_amdgcn_mfma_f32_16x16x32_bf16(a1,e1,re[1][1],0,0,0);
      re[2][0]=__builtin_amdgcn_mfma_f32_16x16x32_bf16(a2,e0,re[2][0],0,0,0);
      re[2][1]=__builtin_amdgcn_mfma_f32_16x16x32_bf16(a2,e1,re[2][1],0,0,0);
    }
    #pragma unroll
    for (int mt=0;mt<3;mt++)
    #pragma unroll
    for (int nt=0;nt<2;nt++){
      int n = wv*32 + nt*16 + nl;
      #pragma unroll
      for (int r=0;r<4;r++){
        int m = mt*16 + quad*4 + r;
        int node = base + m;
        if (m < 36 && node < N_LIGC) RC[(size_t)node*HID + n] = rc[mt][nt][r];
      }
    }
    if (doE){
      #pragma unroll
      for (int mt=0;mt<3;mt++)
      #pragma unroll
      for (int nt=0;nt<2;nt++){
        int n = wv*32 + nt*16 + nl;
        #pragma unroll
        for (int r=0;r<4;r++){
          int m = mt*16 + quad*4 + r;
          int node = base + m;
          if (m < 36 && node < N_LIGC) RE[(size_t)node*HID + n] = re[mt][nt][r];
        }
      }
    }
  }
  if (doOut && isLig && wv < 2){
    int ntw = wv;
    f32x4 o[3]; o[0]=zero4; o[1]=zero4; o[2]=zero4;
    #pragma unroll 2
    for (int k0=0;k0<8;k0++){
      bf16x8 b = *(const bf16x8*)(WoutP + ((size_t)(k0*2 + ntw)*64 + lane)*8);
      #pragma unroll
      for (int mt=0;mt<3;mt++){
        bf16x8 a = *(const bf16x8*)(sH + (mt*16+nl)*264 + k0*32 + quad*8);
        o[mt] = __builtin_amdgcn_mfma_f32_16x16x32_bf16(a,b,o[mt],0,0,0);
      }
    }
    int n = ntw*16 + nl;
    float bb = bout[n];
    #pragma unroll
    for (int mt=0;mt<3;mt++)
    #pragma unroll
    for (int r=0;r<4;r++){
      int m = mt*16 + quad*4 + r;
      int node = base + m;
      if (m < 36 && node < N_LIGC)
        outH[(size_t)node*32 + n] = o[mt][r] + bb;
    }
  }
}

// ---- coord combine (48 edges/block, grid 1024) ----
__global__ __launch_bounds__(256,4) void k_comb_coord(
    const u16* __restrict__ Qb, const float* __restrict__ R,
    const float* __restrict__ xc, float* __restrict__ xn,
    const int* __restrict__ colIdx, const u16* __restrict__ emb0,
    const u16* __restrict__ W1cP, const float* __restrict__ B1,
    const u16* __restrict__ W2p, const float* __restrict__ B2,
    const float* __restrict__ cW3,
    const float* __restrict__ posw, float* __restrict__ outX, int doOut, int l)
{
  __shared__ __align__(16) u16 sQ[48*264];   // Q gather, then M1 in place
  __shared__ __align__(16) u16 sEA[48*40];
  __shared__ float sR[256];
  __shared__ int sCol[48];
  __shared__ float sD[48];
  __shared__ float sCd[48*3];
  __shared__ float sS[48];
  __shared__ float sDot[48][4];

  int row = blockIdx.x, tid = threadIdx.x;
  int lane = tid & 63, ng = tid >> 6;
  int quad = lane >> 4, nl = lane & 15;

  if (tid < 48) sCol[tid] = colIdx[(size_t)row*KNN + tid];
  sR[tid] = R[(size_t)row*HID + tid];
  __syncthreads();
  for (int t = tid; t < 48*32; t += 256){
    int e = t >> 5, q = t & 31;
    uint4 v = ((const uint4*)(Qb + (size_t)sCol[e]*HID))[q];
    *(uint4*)(sQ + e*264 + q*8) = v;
  }
  if (tid < 48){
    int cg = sCol[tid];
    float dx = xc[row*3+0]-xc[cg*3+0];
    float dy = xc[row*3+1]-xc[cg*3+1];
    float dz = xc[row*3+2]-xc[cg*3+2];
    float d = sqrtf(dx*dx+dy*dy+dz*dz + 1e-8f);
    sD[tid] = d;
    float rden = __builtin_amdgcn_rcpf(d + 1.0f);
    sCd[tid*3+0]=dx*rden; sCd[tid*3+1]=dy*rden; sCd[tid*3+2]=dz*rden;
    const unsigned int* ep = (const unsigned int*)(emb0 + ((size_t)row*KNN + tid)*12);
    unsigned int* dd = (unsigned int*)(sEA + tid*40 + 12);
    #pragma unroll
    for (int i=0;i<6;i++) dd[i] = ep[i];
    u16* ea = sEA + tid*40;
    #pragma unroll
    for (int i=24;i<32;i++) ea[i] = 0;
  }
  __syncthreads();
  for (int t=tid; t<288; t+=256){
    int e = t/6, i = t - 6*e;
    float fr = 0.41887903f * (float)(1 << (2*i));
    float x = sD[e]*fr;
    u16* ea = sEA + e*40;
    ea[i]   = f2b(__sinf(x));
    ea[6+i] = f2b(__cosf(x));
  }
  __syncthreads();

  f32x4 zero4 = {0.f,0.f,0.f,0.f};
  f32x4 acc[3][4];
  #pragma unroll
  for (int i=0;i<3;i++){ acc[i][0]=zero4; acc[i][1]=zero4; acc[i][2]=zero4; acc[i][3]=zero4; }
  {
    const u16* Wc = W1cP + (size_t)l*32*HID;
    const u16* wb = Wc + ((size_t)(ng*4)*64 + lane)*8;
    bf16x8 b0 = *(const bf16x8*)(wb);
    bf16x8 b1 = *(const bf16x8*)(wb + 512);
    bf16x8 b2 = *(const bf16x8*)(wb + 1024);
    bf16x8 b3 = *(const bf16x8*)(wb + 1536);
    bf16x8 a0 = *(const bf16x8*)(sEA + (0*16+nl)*40 + quad*8);
    bf16x8 a1 = *(const bf16x8*)(sEA + (1*16+nl)*40 + quad*8);
    bf16x8 a2 = *(const bf16x8*)(sEA + (2*16+nl)*40 + quad*8);
    acc[0][0]=__builtin_amdgcn_mfma_f32_16x16x32_bf16(a0,b0,acc[0][0],0,0,0);
    acc[0][1]=__builtin_amdgcn_mfma_f32_16x16x32_bf16(a0,b1,acc[0][1],0,0,0);
    acc[0][2]=__builtin_amdgcn_mfma_f32_16x16x32_bf16(a0,b2,acc[0][2],0,0,0);
    acc[0][3]=__builtin_amdgcn_mfma_f32_16x16x32_bf16(a0,b3,acc[0][3],0,0,0);
    acc[1][0]=__builtin_amdgcn_mfma_f32_16x16x32_bf16(a1,b0,acc[1][0],0,0,0);
    acc[1][1]=__builtin_amdgcn_mfma_f32_16x16x32_bf16(a1,b1,acc[1][1],0,0,0);
    acc[1][2]=__builtin_amdgcn_mfma_f32_16x16x32_bf16(a1,b2,acc[1][2],0,0,0);
    acc[1][3]=__builtin_amdgcn_mfma_f32_16x16x32_bf16(a1,b3,acc[1][3],0,0,0);
    acc[2][0]=__builtin_amdgcn_mfma_f32_16x16x32_bf16(a2,b0,acc[2][0],0,0,0);
    acc[2][1]=__builtin_amdgcn_mfma_f32_16x16x32_bf16(a2,b1,acc[2][1],0,0,0);
    acc[2][2]=__builtin_amdgcn_mfma_f32_16x16x32_bf16(a2,b2,acc[2][2],0,0,0);
    acc[2][3]=__builtin_amdgcn_mfma_f32_16x16x32_bf16(a2,b3,acc[2][3],0,0,0);
  }
  // in-place M1 epilogue (per-thread RMW ownership; A operand was in sEA)
  #pragma unroll
  for (int mt=0;mt<3;mt++)
  #pragma unroll
  for (int nt=0;nt<4;nt++){
    int n = ng*64 + nt*16 + nl;
    float bb = B1[l*HID + n] + sR[n];
    #pragma unroll
    for (int r=0;r<4;r++){
      int m = mt*16 + quad*4 + r;
      float v = acc[mt][nt][r] + bb + b2f(sQ[m*264 + n]);
      sQ[m*264 + n] = f2b(silu_f(v));
    }
  }
  __syncthreads();

  f32x4 acc2[3][4];
  #pragma unroll
  for (int i=0;i<3;i++){ acc2[i][0]=zero4; acc2[i][1]=zero4; acc2[i][2]=zero4; acc2[i][3]=zero4; }
  const u16* W2 = W2p + (size_t)l*HID*HID;
  #pragma unroll 2
  for (int k0=0;k0<8;k0++){
    bf16x8 a0 = *(const bf16x8*)(sQ + (0*16+nl)*264 + k0*32 + quad*8);
    bf16x8 a1 = *(const bf16x8*)(sQ + (1*16+nl)*264 + k0*32 + quad*8);
    bf16x8 a2 = *(const bf16x8*)(sQ + (2*16+nl)*264 + k0*32 + quad*8);
    const u16* wb = W2 + ((size_t)(k0*16 + ng*4)*64 + lane)*8;
    bf16x8 b0 = *(const bf16x8*)(wb);
    bf16x8 b1 = *(const bf16x8*)(wb + 512);
    bf16x8 b2 = *(const bf16x8*)(wb + 1024);
    bf16x8 b3 = *(const bf16x8*)(wb + 1536);
    acc2[0][0]=__builtin_amdgcn_mfma_f32_16x16x32_bf16(a0,b0,acc2[0][0],0,0,0);
    acc2[0][1]=__builtin_amdgcn_mfma_f32_16x16x32_bf16(a0,b1,acc2[0][1],0,0,0);
    acc2[0][2]=__builtin_amdgcn_mfma_f32_16x16x32_bf16(a0,b2,acc2[0][2],0,0,0);
    acc2[0][3]=__builtin_amdgcn_mfma_f32_16x16x32_bf16(a0,b3,acc2[0][3],0,0,0);
    acc2[1][0]=__builtin_amdgcn_mfma_f32_16x16x32_bf16(a1,b0,acc2[1][0],0,0,0);
    acc2[1][1]=__builtin_amdgcn_mfma_f32_16x16x32_bf16(a1,b1,acc2[1][1],0,0,0);
    acc2[1][2]=__builtin_amdgcn_mfma_f32_16x16x32_bf16(a1,b2,acc2[1][2],0,0,0);
    acc2[1][3]=__builtin_amdgcn_mfma_f32_16x16x32_bf16(a1,b3,acc2[1][3],0,0,0);
    acc2[2][0]=__builtin_amdgcn_mfma_f32_16x16x32_bf16(a2,b0,acc2[2][0],0,0,0);
    acc2[2][1]=__builtin_amdgcn_mfma_f32_16x16x32_bf16(a2,b1,acc2[2][1],0,0,0);
    acc2[2][2]=__builtin_amdgcn_mfma_f32_16x16x32_bf16(a2,b2,acc2[2][2],0,0,0);
    acc2[2][3]=__builtin_amdgcn_mfma_f32_16x16x32_bf16(a2,b3,acc2[2][3],0,0,0);
  }
  // register epilogue: silu + dot with cW3, shfl-reduce over nl
  float cw[4], bb2[4];
  #pragma unroll
  for (int nt=0;nt<4;nt++){
    int n = ng*64 + nt*16 + nl;
    cw[nt]  = cW3[l*HID + n];
    bb2[nt] = B2[l*HID + n];
  }
  float dotp[3][4];
  #pragma unroll
  for (int mt=0;mt<3;mt++){
    #pragma unroll
    for (int r=0;r<4;r++) dotp[mt][r] = 0.f;
    #pragma unroll
    for (int nt=0;nt<4;nt++){
      #pragma unroll
      for (int r=0;r<4;r++){
        float s = silu_f(acc2[mt][nt][r] + bb2[nt]);
        dotp[mt][r] += s*cw[nt];
      }
    }
  }
  #pragma unroll
  for (int off=1; off<16; off<<=1){
    #pragma unroll
    for (int mt=0;mt<3;mt++)
    #pragma unroll
    for (int r=0;r<4;r++)
      dotp[mt][r] += __shfl_xor(dotp[mt][r], off);
  }
  if (nl == 0){
    #pragma unroll
    for (int mt=0;mt<3;mt++)
    #pragma unroll
    for (int r=0;r<4;r++)
      sDot[mt*16 + quad*4 + r][ng] = dotp[mt][r];
  }
  __syncthreads();
  if (tid < 48) sS[tid] = sDot[tid][0]+sDot[tid][1]+sDot[tid][2]+sDot[tid][3];
  __syncthreads();
  if (tid < 3){
    float u = 0.f;
    #pragma unroll 4
    for (int e=0;e<48;e++) u += sCd[e*3+tid]*sS[e];
    float nv = xc[row*3+tid] + u*0.2f;
    xn[row*3+tid] = nv;
    if (doOut) outX[row*3+tid] = nv*posw[0];
  }
}

extern "C" void kernel_launch(void* const* d_in, const int* in_sizes, int n_in,
                              void* d_out, int out_size, void* d_ws, size_t ws_size,
                              hipStream_t stream)
{
  const float* protPos = (const float*)d_in[0];
  const int*   protEle = (const int*)d_in[1];
  const int*   protAA  = (const int*)d_in[2];
  const int*   protBB  = (const int*)d_in[3];
  const float* XtPos   = (const float*)d_in[4];
  const float* XtFeat  = (const float*)d_in[5];
  const int*   tArr    = (const int*)d_in[6];
  const float* WtTime  = (const float*)d_in[7];
  const float* Wele    = (const float*)d_in[8];
  const float* Waa     = (const float*)d_in[9];
  const float* Wbb     = (const float*)d_in[10];
  const float* Win     = (const float*)d_in[11];
  const float* bin     = (const float*)d_in[12];
  const float* Wout    = (const float*)d_in[13];
  const float* bout    = (const float*)d_in[14];
  const float* eW1     = (const float*)d_in[15];
  const float* eB1     = (const float*)d_in[16];
  const float* eW2     = (const float*)d_in[17];
  const float* eB2     = (const float*)d_in[18];
  const float* attW    = (const float*)d_in[19];
  const float* attB    = (const float*)d_in[20];
  const float* nW1     = (const float*)d_in[21];
  const float* nB1     = (const float*)d_in[22];
  const float* nW2     = (const float*)d_in[23];
  const float* nB2     = (const float*)d_in[24];
  const float* cW1     = (const float*)d_in[25];
  const float* cB1     = (const float*)d_in[26];
  const float* cW2     = (const float*)d_in[27];
  const float* cB2     = (const float*)d_in[28];
  const float* cW3     = (const float*)d_in[29];
  const float* posw    = (const float*)d_in[30];

  float* fp = (float*)d_ws;
  float* X0   = fp;               fp += NTOT*3;
  float* X1   = fp;               fp += NTOT*3;
  float* h    = fp;               fp += (size_t)NTOT*HID;
  float* RC   = fp;               fp += (size_t)N_LIGC*HID;
  float* RE   = fp;               fp += (size_t)N_LIGC*HID;
  int*   col  = (int*)fp;         fp += ETOT;
  u16*   up   = (u16*)fp;
  u16* emb0   = up;               up += (size_t)ETOT*12;
  u16* h_bf   = up;               up += (size_t)NTOT*HID;
  u16* agg_bf = up;               up += (size_t)N_LIGC*HID;
  u16* QbE    = up;               up += (size_t)NTOT*HID;
  u16* QbC    = up;               up += (size_t)NTOT*HID;
  u16* eW1abP = up;               up += (size_t)DEPTHC*512*HID;
  u16* eW1cP  = up;               up += (size_t)DEPTHC*32*HID;
  u16* eW2p   = up;               up += (size_t)DEPTHC*HID*HID;
  u16* nW1p   = up;               up += (size_t)DEPTHC*512*HID;
  u16* nW2p   = up;               up += (size_t)DEPTHC*HID*HID;
  u16* cW1abP = up;               up += (size_t)DEPTHC*512*HID;
  u16* cW1cP  = up;               up += (size_t)DEPTHC*32*HID;
  u16* cW2p   = up;               up += (size_t)DEPTHC*HID*HID;
  u16* WoutP  = up;               up += (size_t)256*32;

  k_prep<<<PACK_BLKS + NTOT/8,256,0,stream>>>(eW1,eW2,nW1,nW2,cW1,cW2,Wout,
      eW1abP,eW1cP,eW2p,nW1p,nW2p,cW1abP,cW1cP,cW2p,WoutP,
      protPos,protEle,protAA,protBB,XtPos,XtFeat,
      tArr,WtTime,Wele,Waa,Wbb,Win,bin,X0,X1,h,h_bf);
  k_knn<<<N_LIGC,256,0,stream>>>(X0,col,emb0);
  k_pq<<<256,512,0,stream>>>(h_bf,eW1abP,RE,QbE,0);

  float* xc = X0; float* xn = X1;
  float* outF = (float*)d_out;
  for (int l=0;l<DEPTHC;l++){
    k_comb_edge<<<N_LIGC,256,0,stream>>>(QbE,RE,xc,col,emb0,eW1cP,eB1,eW2p,eB2,attW,attB,agg_bf,l);
    const u16* eNext = eW1abP + (size_t)((l+1)%DEPTHC)*512*HID;
    k_node<<<256,512,0,stream>>>(h,h_bf,agg_bf,nW1p,nB1,nW2p,nB2,
        cW1abP,QbC,RC, eNext,QbE,RE,(l<DEPTHC-1)?1:0,
        WoutP,bout, outF+3072, (l==DEPTHC-1)?1:0, l);
    k_comb_coord<<<N_LIGC,256,0,stream>>>(QbC,RC,xc,xn,col,emb0,cW1cP,cB1,cW2p,cB2,cW3,
        posw, outF, (l==DEPTHC-1)?1:0, l);
    float* t2=xc; xc=xn; xn=t2;
  }
}

// Round 10
// 478.220 us; speedup vs baseline: 1.0027x; 1.0027x over previous
//
#include <hip/hip_runtime.h>
#include <hip/hip_bf16.h>
#include <math.h>

#define N_LIGC 1024
#define NTOT 9216
#define KNN 48
#define HID 256
#define DEPTHC 5
#define ETOT (N_LIGC*KNN)
#define KBINS 4096
#define PACK_BLKS 1484

typedef unsigned short u16;
typedef __attribute__((ext_vector_type(8))) short bf16x8;
typedef __attribute__((ext_vector_type(4))) float f32x4;

__device__ __forceinline__ float freq_f(int i){
  double p = (double)(1 << (2*i));
  return (float)((2.0*3.14159265358979323846)*p/15.0);
}
// fast silu/sigmoid: native exp + single v_rcp_f32 (avoids IEEE div sequence)
__device__ __forceinline__ float silu_f(float v){
  return v*__builtin_amdgcn_rcpf(1.0f+__expf(-v));
}
__device__ __forceinline__ float sigm_f(float v){
  return __builtin_amdgcn_rcpf(1.0f+__expf(-v));
}
// branchless RNE float->bf16
__device__ __forceinline__ u16 f2b(float f){
  unsigned int u = __float_as_uint(f);
  return (u16)((u + 0x7fffu + ((u>>16)&1u)) >> 16);
}
__device__ __forceinline__ float b2f(u16 u){
  union { unsigned int i; float f; } c; c.i = ((unsigned int)u)<<16; return c.f;
}
// precise RNE (for weight packing, matches __float2bfloat16)
__device__ __forceinline__ u16 f2b_p(float f){
  union { __hip_bfloat16 h; u16 u; } c; c.h = __float2bfloat16(f); return c.u;
}

// ---- pack fp32 [L][srcK][N] rows [kOff,kOff+Keff) -> bf16 B-frag layout
__device__ __forceinline__ void pack_one(const float* __restrict__ src,
    u16* __restrict__ dst, int srcK, int kOff, int Keff, int Kp, int N, int idx)
{
  int lane = idx & 63;
  int rest = idx >> 6;
  int Nt = N >> 4;
  int n0 = rest % Nt;
  int rest2 = rest / Nt;
  int Kt = Kp >> 5;
  int k0 = rest2 % Kt;
  int layer = rest2 / Kt;
  int kq = lane >> 4, nl = lane & 15;
  int kb = k0*32 + kq*8, n = n0*16 + nl;
  u16 o[8];
  #pragma unroll
  for (int j=0;j<8;j++){
    int k = kb + j;
    float v = (k < Keff) ? src[((size_t)layer*srcK + kOff + k)*N + n] : 0.f;
    o[j] = f2b_p(v);
  }
  *(uint4*)(dst + (size_t)idx*8) = *(uint4*)o;
}

// ---- merged: weight pack (blocks 0..1483) + embed/h-init (blocks 1484..) ----
__global__ __launch_bounds__(256) void k_prep(
    const float* eW1, const float* eW2, const float* nW1, const float* nW2,
    const float* cW1, const float* cW2, const float* Wout,
    u16* eW1abP, u16* eW1cP, u16* eW2p, u16* nW1p, u16* nW2p,
    u16* cW1abP, u16* cW1cP, u16* cW2p, u16* WoutP,
    const float* __restrict__ protPos, const int* __restrict__ protEle,
    const int* __restrict__ protAA, const int* __restrict__ protBB,
    const float* __restrict__ XtPos, const float* __restrict__ XtFeat,
    const int* __restrict__ tArr, const float* __restrict__ WtTime,
    const float* __restrict__ Wele, const float* __restrict__ Waa,
    const float* __restrict__ Wbb,
    const float* __restrict__ Win, const float* __restrict__ bin,
    float* __restrict__ X0, float* __restrict__ X1,
    float* __restrict__ h, u16* __restrict__ h_bf)
{
  __shared__ float sF[8*40];
  if (blockIdx.x < PACK_BLKS){
    int idx = blockIdx.x*256 + threadIdx.x;
    if (idx < 81920){ pack_one(eW1, eW1abP, 536, 0,   512, 512, 256, idx); return; } idx -= 81920;
    if (idx < 5120 ){ pack_one(eW1, eW1cP,  536, 512, 24,  32,  256, idx); return; } idx -= 5120;
    if (idx < 40960){ pack_one(eW2, eW2p,   256, 0,   256, 256, 256, idx); return; } idx -= 40960;
    if (idx < 81920){ pack_one(nW1, nW1p,   512, 0,   512, 512, 256, idx); return; } idx -= 81920;
    if (idx < 40960){ pack_one(nW2, nW2p,   256, 0,   256, 256, 256, idx); return; } idx -= 40960;
    if (idx < 81920){ pack_one(cW1, cW1abP, 536, 0,   512, 512, 256, idx); return; } idx -= 81920;
    if (idx < 5120 ){ pack_one(cW1, cW1cP,  536, 512, 24,  32,  256, idx); return; } idx -= 5120;
    if (idx < 40960){ pack_one(cW2, cW2p,   256, 0,   256, 256, 256, idx); return; } idx -= 40960;
    if (idx < 1024 ){ pack_one(Wout, WoutP, 256, 0,   256, 256, 32,  idx); return; }
    return;
  }
  int blk=blockIdx.x - PACK_BLKS, tid=threadIdx.x;
  int n0=blk*8;
  for (int x=tid; x<344; x+=256){
    if (x < 320){
      int n = x/40, k = x%40;
      int node = n0+n;
      float v;
      if (node < N_LIGC){
        if (k < 32) v = XtFeat[node*32+k];
        else        v = WtTime[tArr[node]*8 + (k-32)];
      } else {
        int p = node - N_LIGC;
        if (k < 16)      v = Wele[protEle[p]*16 + k];
        else if (k < 32) v = Waa[protAA[p]*16 + (k-16)];
        else             v = Wbb[protBB[p]*8 + (k-32)];
      }
      sF[n*40+k] = v;
    } else {
      int r = x-320; int n = r/3, c = r%3;
      int node = n0+n;
      float v = (node < N_LIGC) ? XtPos[node*3+c] : protPos[(node-N_LIGC)*3+c];
      X0[node*3+c] = v; X1[node*3+c] = v;
    }
  }
  __syncthreads();
  float acc[8];
  float b=bin[tid];
  #pragma unroll
  for (int n=0;n<8;n++) acc[n]=b;
  for (int k=0;k<40;k++){
    float w=Win[k*HID+tid];
    #pragma unroll
    for (int n=0;n<8;n++) acc[n]+=sF[n*40+k]*w;
  }
  #pragma unroll
  for (int n=0;n<8;n++){
    h[(size_t)(n0+n)*HID+tid]=acc[n];
    h_bf[(size_t)(n0+n)*HID+tid]=f2b_p(acc[n]);
  }
}

// ---- merged KNN + PQ (independent, both depend only on k_prep) ----
// blocks 0..255: pq (512 threads); blocks 256..1279: knn (threads>=256 retire).
// Shared-mem pools aliased (pq sA 25.3KB / knn arrays 25.3KB).
__global__ __launch_bounds__(512,1) void k_knn_pq(
    const float* __restrict__ X, int* __restrict__ col, u16* __restrict__ emb0,
    const u16* __restrict__ h_bf, const u16* __restrict__ Wab,
    float* __restrict__ R, u16* __restrict__ Qb)
{
  __shared__ __align__(16) unsigned char smem[25856];
  int tid = threadIdx.x;
  if (blockIdx.x < 256){
    // ---- pq body: grid 256, 512 threads, 36 nodes padded to 48 ----
    u16* sA = (u16*)smem;
    int blk=blockIdx.x;
    int lane=tid&63, wv=tid>>6, quad=lane>>4, nl=lane&15;
    int base = blk*36;
    for (int t=tid; t<48*32; t+=512){
      int i=t>>5, q=t&31;
      uint4 v;
      if (i < 36) v = ((const uint4*)(h_bf + (size_t)(base+i)*HID))[q];
      else { v.x=0u; v.y=0u; v.z=0u; v.w=0u; }
      *(uint4*)(sA + i*264 + q*8) = v;
    }
    __syncthreads();
    const u16* Wl = Wab;   // l = 0
    f32x4 zero4 = {0.f,0.f,0.f,0.f};
    f32x4 aQ[3][2];
    #pragma unroll
    for (int i=0;i<3;i++){ aQ[i][0]=zero4; aQ[i][1]=zero4; }
    #pragma unroll 2
    for (int k0=0;k0<8;k0++){
      bf16x8 a0 = *(const bf16x8*)(sA + (0*16+nl)*264 + k0*32 + quad*8);
      bf16x8 a1 = *(const bf16x8*)(sA + (1*16+nl)*264 + k0*32 + quad*8);
      bf16x8 a2 = *(const bf16x8*)(sA + (2*16+nl)*264 + k0*32 + quad*8);
      const u16* wb = Wl + ((size_t)((k0+8)*16 + wv*2)*64 + lane)*8;
      bf16x8 b0 = *(const bf16x8*)(wb);
      bf16x8 b1 = *(const bf16x8*)(wb + 512);
      aQ[0][0]=__builtin_amdgcn_mfma_f32_16x16x32_bf16(a0,b0,aQ[0][0],0,0,0);
      aQ[0][1]=__builtin_amdgcn_mfma_f32_16x16x32_bf16(a0,b1,aQ[0][1],0,0,0);
      aQ[1][0]=__builtin_amdgcn_mfma_f32_16x16x32_bf16(a1,b0,aQ[1][0],0,0,0);
      aQ[1][1]=__builtin_amdgcn_mfma_f32_16x16x32_bf16(a1,b1,aQ[1][1],0,0,0);
      aQ[2][0]=__builtin_amdgcn_mfma_f32_16x16x32_bf16(a2,b0,aQ[2][0],0,0,0);
      aQ[2][1]=__builtin_amdgcn_mfma_f32_16x16x32_bf16(a2,b1,aQ[2][1],0,0,0);
    }
    #pragma unroll
    for (int mt=0;mt<3;mt++)
    #pragma unroll
    for (int nt=0;nt<2;nt++){
      int n = wv*32 + nt*16 + nl;
      #pragma unroll
      for (int r=0;r<4;r++){
        int m = mt*16 + quad*4 + r;
        if (m < 36) Qb[(size_t)(base+m)*HID + n] = f2b(aQ[mt][nt][r]);
      }
    }
    if (base < N_LIGC){
      f32x4 aR[3][2];
      #pragma unroll
      for (int i=0;i<3;i++){ aR[i][0]=zero4; aR[i][1]=zero4; }
      #pragma unroll 2
      for (int k0=0;k0<8;k0++){
        bf16x8 a0 = *(const bf16x8*)(sA + (0*16+nl)*264 + k0*32 + quad*8);
        bf16x8 a1 = *(const bf16x8*)(sA + (1*16+nl)*264 + k0*32 + quad*8);
        bf16x8 a2 = *(const bf16x8*)(sA + (2*16+nl)*264 + k0*32 + quad*8);
        const u16* wb = Wl + ((size_t)(k0*16 + wv*2)*64 + lane)*8;
        bf16x8 b0 = *(const bf16x8*)(wb);
        bf16x8 b1 = *(const bf16x8*)(wb + 512);
        aR[0][0]=__builtin_amdgcn_mfma_f32_16x16x32_bf16(a0,b0,aR[0][0],0,0,0);
        aR[0][1]=__builtin_amdgcn_mfma_f32_16x16x32_bf16(a0,b1,aR[0][1],0,0,0);
        aR[1][0]=__builtin_amdgcn_mfma_f32_16x16x32_bf16(a1,b0,aR[1][0],0,0,0);
        aR[1][1]=__builtin_amdgcn_mfma_f32_16x16x32_bf16(a1,b1,aR[1][1],0,0,0);
        aR[2][0]=__builtin_amdgcn_mfma_f32_16x16x32_bf16(a2,b0,aR[2][0],0,0,0);
        aR[2][1]=__builtin_amdgcn_mfma_f32_16x16x32_bf16(a2,b1,aR[2][1],0,0,0);
      }
      #pragma unroll
      for (int mt=0;mt<3;mt++)
      #pragma unroll
      for (int nt=0;nt<2;nt++){
        int n = wv*32 + nt*16 + nl;
        #pragma unroll
        for (int r=0;r<4;r++){
          int m = mt*16 + quad*4 + r;
          int node = base + m;
          if (m < 36 && node < N_LIGC) R[(size_t)node*HID + n] = aR[mt][nt][r];
        }
      }
    }
    return;
  }
  // ---- knn body: blocks 256..1279, only threads 0..255 participate ----
  if (tid >= 256) return;
  unsigned int* hist  = (unsigned int*)smem;             // 16384 B
  int*          candI = (int*)(smem + 16384);            // 4096 B
  float*        candV = (float*)(smem + 20480);          // 4096 B
  unsigned int* scanb = (unsigned int*)(smem + 24576);   // 1024 B
  float*        selD  = (float*)(smem + 25600);          // 192 B
  int*          sInt  = (int*)(smem + 25792);            // sB, sCbase, sChunk, sNcand
  int b = blockIdx.x - 256;
  for (int i=tid;i<KBINS;i+=256) hist[i]=0u;
  if (tid==0){ sInt[3]=0; }
  float px = X[b*3+0], py = X[b*3+1], pz = X[b*3+2];
  __syncthreads();
  float d2v[36];
  float mn = INFINITY;
  #pragma unroll
  for (int j=0;j<36;j++){
    int i = tid + 256*j;
    float dx = __fsub_rn(px, X[i*3+0]);
    float dy = __fsub_rn(py, X[i*3+1]);
    float dz = __fsub_rn(pz, X[i*3+2]);
    float d2 = __fadd_rn(__fadd_rn(__fmul_rn(dx,dx),__fmul_rn(dy,dy)),__fmul_rn(dz,dz));
    if (i==b) d2 = INFINITY;
    d2v[j] = d2;
    mn = fminf(mn, d2);
  }
  {
    unsigned mkey = __float_as_uint(mn) >> 19;
    if (mkey >= KBINS) mkey = KBINS-1;
    atomicAdd(&hist[mkey], 1u);
  }
  __syncthreads();
  unsigned s=0;
  {
    #pragma unroll 4
    for (int k=0;k<16;k++) s += hist[tid*16+k];
    scanb[tid]=s;
  }
  __syncthreads();
  #pragma unroll
  for (int off=1; off<256; off<<=1){
    unsigned v = (tid>=off) ? scanb[tid-off] : 0u;
    __syncthreads();
    scanb[tid] += v;
    __syncthreads();
  }
  {
    unsigned incl = scanb[tid];
    unsigned excl = incl - s;
    if (excl < (unsigned)KNN && incl >= (unsigned)KNN){ sInt[2] = tid; sInt[1] = (int)excl; }
  }
  __syncthreads();
  if (tid==0){
    unsigned c = (unsigned)sInt[1]; int bin = sInt[2]*16;
    for (;;bin++){
      unsigned hh = hist[bin];
      if (c + hh >= (unsigned)KNN) break;
      c += hh;
    }
    sInt[0] = bin;
  }
  __syncthreads();
  int Bp = sInt[0];
  #pragma unroll
  for (int j=0;j<36;j++){
    float d2 = d2v[j];
    int key = (int)(__float_as_uint(d2) >> 19);
    if (key <= Bp){
      int c = atomicAdd(&sInt[3], 1);
      if (c < 1024){ candI[c] = tid + 256*j; candV[c] = d2; }
    }
  }
  __syncthreads();
  {
    int m = sInt[3]; if (m > 1024) m = 1024;
    for (int c = tid; c < m; c += 256){
      float v = candV[c]; int idx = candI[c];
      int rank = 0;
      for (int o = 0; o < m; o++){
        float ov = candV[o];
        if (ov < v || (ov == v && candI[o] < idx)) rank++;
      }
      if (rank < KNN){ col[b*KNN+rank] = idx; selD[rank] = v; }
    }
  }
  __syncthreads();
  if (tid < KNN){
    float d = sqrtf(selD[tid] + 1e-8f);
    int base = (b*KNN+tid)*12;
    #pragma unroll
    for (int i=0;i<6;i++){
      float fr = freq_f(i);
      emb0[base+i]   = f2b_p(sinf(d*fr));
      emb0[base+6+i] = f2b_p(cosf(d*fr));
    }
  }
}

// ---- edge combine (48 edges/block, grid 1024) ----
__global__ __launch_bounds__(256,4) void k_comb_edge(
    const u16* __restrict__ Qb, const float* __restrict__ R,
    const float* __restrict__ xc,
    const int* __restrict__ colIdx, const u16* __restrict__ emb0,
    const u16* __restrict__ W1cP, const float* __restrict__ B1,
    const u16* __restrict__ W2p, const float* __restrict__ B2,
    const float* __restrict__ attW, const float* __restrict__ attB,
    u16* __restrict__ agg_bf, int l)
{
  __shared__ __align__(16) u16 sQ[48*264];   // Q gather, then M1 in place
  __shared__ __align__(16) u16 sEA[48*40];
  __shared__ float sR[256];
  __shared__ int sCol[48];
  __shared__ float sD[48];
  __shared__ float sSig[48];
  __shared__ float sDot[48][4];

  int row = blockIdx.x, tid = threadIdx.x;
  int lane = tid & 63, ng = tid >> 6;
  int quad = lane >> 4, nl = lane & 15;

  if (tid < 48) sCol[tid] = colIdx[(size_t)row*KNN + tid];
  sR[tid] = R[(size_t)row*HID + tid];
  __syncthreads();
  for (int t = tid; t < 48*32; t += 256){
    int e = t >> 5, q = t & 31;
    uint4 v = ((const uint4*)(Qb + (size_t)sCol[e]*HID))[q];
    *(uint4*)(sQ + e*264 + q*8) = v;
  }
  if (tid < 48){
    int cg = sCol[tid];
    float dx = xc[row*3+0]-xc[cg*3+0];
    float dy = xc[row*3+1]-xc[cg*3+1];
    float dz = xc[row*3+2]-xc[cg*3+2];
    float d = sqrtf(dx*dx+dy*dy+dz*dz + 1e-8f);
    sD[tid] = d;
    const unsigned int* ep = (const unsigned int*)(emb0 + ((size_t)row*KNN + tid)*12);
    unsigned int* dd = (unsigned int*)(sEA + tid*40 + 12);
    #pragma unroll
    for (int i=0;i<6;i++) dd[i] = ep[i];
    u16* ea = sEA + tid*40;
    #pragma unroll
    for (int i=24;i<32;i++) ea[i] = 0;
  }
  __syncthreads();
  for (int t=tid; t<288; t+=256){
    int e = t/6, i = t - 6*e;
    float fr = 0.41887903f * (float)(1 << (2*i));
    float x = sD[e]*fr;
    u16* ea = sEA + e*40;
    ea[i]   = f2b(__sinf(x));
    ea[6+i] = f2b(__cosf(x));
  }
  __syncthreads();

  f32x4 zero4 = {0.f,0.f,0.f,0.f};
  f32x4 acc[3][4];
  #pragma unroll
  for (int i=0;i<3;i++){ acc[i][0]=zero4; acc[i][1]=zero4; acc[i][2]=zero4; acc[i][3]=zero4; }
  {
    const u16* Wc = W1cP + (size_t)l*32*HID;
    const u16* wb = Wc + ((size_t)(ng*4)*64 + lane)*8;
    bf16x8 b0 = *(const bf16x8*)(wb);
    bf16x8 b1 = *(const bf16x8*)(wb + 512);
    bf16x8 b2 = *(const bf16x8*)(wb + 1024);
    bf16x8 b3 = *(const bf16x8*)(wb + 1536);
    bf16x8 a0 = *(const bf16x8*)(sEA + (0*16+nl)*40 + quad*8);
    bf16x8 a1 = *(const bf16x8*)(sEA + (1*16+nl)*40 + quad*8);
    bf16x8 a2 = *(const bf16x8*)(sEA + (2*16+nl)*40 + quad*8);
    acc[0][0]=__builtin_amdgcn_mfma_f32_16x16x32_bf16(a0,b0,acc[0][0],0,0,0);
    acc[0][1]=__builtin_amdgcn_mfma_f32_16x16x32_bf16(a0,b1,acc[0][1],0,0,0);
    acc[0][2]=__builtin_amdgcn_mfma_f32_16x16x32_bf16(a0,b2,acc[0][2],0,0,0);
    acc[0][3]=__builtin_amdgcn_mfma_f32_16x16x32_bf16(a0,b3,acc[0][3],0,0,0);
    acc[1][0]=__builtin_amdgcn_mfma_f32_16x16x32_bf16(a1,b0,acc[1][0],0,0,0);
    acc[1][1]=__builtin_amdgcn_mfma_f32_16x16x32_bf16(a1,b1,acc[1][1],0,0,0);
    acc[1][2]=__builtin_amdgcn_mfma_f32_16x16x32_bf16(a1,b2,acc[1][2],0,0,0);
    acc[1][3]=__builtin_amdgcn_mfma_f32_16x16x32_bf16(a1,b3,acc[1][3],0,0,0);
    acc[2][0]=__builtin_amdgcn_mfma_f32_16x16x32_bf16(a2,b0,acc[2][0],0,0,0);
    acc[2][1]=__builtin_amdgcn_mfma_f32_16x16x32_bf16(a2,b1,acc[2][1],0,0,0);
    acc[2][2]=__builtin_amdgcn_mfma_f32_16x16x32_bf16(a2,b2,acc[2][2],0,0,0);
    acc[2][3]=__builtin_amdgcn_mfma_f32_16x16x32_bf16(a2,b3,acc[2][3],0,0,0);
  }
  // in-place M1 epilogue: per-thread RMW ownership; A operand lives in sEA
  #pragma unroll
  for (int mt=0;mt<3;mt++)
  #pragma unroll
  for (int nt=0;nt<4;nt++){
    int n = ng*64 + nt*16 + nl;
    float bb = B1[l*HID + n] + sR[n];
    #pragma unroll
    for (int r=0;r<4;r++){
      int m = mt*16 + quad*4 + r;
      float v = acc[mt][nt][r] + bb + b2f(sQ[m*264 + n]);
      sQ[m*264 + n] = f2b(silu_f(v));
    }
  }
  __syncthreads();

  f32x4 acc2[3][4];
  #pragma unroll
  for (int i=0;i<3;i++){ acc2[i][0]=zero4; acc2[i][1]=zero4; acc2[i][2]=zero4; acc2[i][3]=zero4; }
  const u16* W2 = W2p + (size_t)l*HID*HID;
  #pragma unroll 2
  for (int k0=0;k0<8;k0++){
    bf16x8 a0 = *(const bf16x8*)(sQ + (0*16+nl)*264 + k0*32 + quad*8);
    bf16x8 a1 = *(const bf16x8*)(sQ + (1*16+nl)*264 + k0*32 + quad*8);
    bf16x8 a2 = *(const bf16x8*)(sQ + (2*16+nl)*264 + k0*32 + quad*8);
    const u16* wb = W2 + ((size_t)(k0*16 + ng*4)*64 + lane)*8;
    bf16x8 b0 = *(const bf16x8*)(wb);
    bf16x8 b1 = *(const bf16x8*)(wb + 512);
    bf16x8 b2 = *(const bf16x8*)(wb + 1024);
    bf16x8 b3 = *(const bf16x8*)(wb + 1536);
    acc2[0][0]=__builtin_amdgcn_mfma_f32_16x16x32_bf16(a0,b0,acc2[0][0],0,0,0);
    acc2[0][1]=__builtin_amdgcn_mfma_f32_16x16x32_bf16(a0,b1,acc2[0][1],0,0,0);
    acc2[0][2]=__builtin_amdgcn_mfma_f32_16x16x32_bf16(a0,b2,acc2[0][2],0,0,0);
    acc2[0][3]=__builtin_amdgcn_mfma_f32_16x16x32_bf16(a0,b3,acc2[0][3],0,0,0);
    acc2[1][0]=__builtin_amdgcn_mfma_f32_16x16x32_bf16(a1,b0,acc2[1][0],0,0,0);
    acc2[1][1]=__builtin_amdgcn_mfma_f32_16x16x32_bf16(a1,b1,acc2[1][1],0,0,0);
    acc2[1][2]=__builtin_amdgcn_mfma_f32_16x16x32_bf16(a1,b2,acc2[1][2],0,0,0);
    acc2[1][3]=__builtin_amdgcn_mfma_f32_16x16x32_bf16(a1,b3,acc2[1][3],0,0,0);
    acc2[2][0]=__builtin_amdgcn_mfma_f32_16x16x32_bf16(a2,b0,acc2[2][0],0,0,0);
    acc2[2][1]=__builtin_amdgcn_mfma_f32_16x16x32_bf16(a2,b1,acc2[2][1],0,0,0);
    acc2[2][2]=__builtin_amdgcn_mfma_f32_16x16x32_bf16(a2,b2,acc2[2][2],0,0,0);
    acc2[2][3]=__builtin_amdgcn_mfma_f32_16x16x32_bf16(a2,b3,acc2[2][3],0,0,0);
  }
  // M2 epilogue fully in registers
  float aw[4], bb2[4];
  #pragma unroll
  for (int nt=0;nt<4;nt++){
    int n = ng*64 + nt*16 + nl;
    aw[nt]  = attW[l*HID + n];
    bb2[nt] = B2[l*HID + n];
  }
  float dotp[3][4];
  #pragma unroll
  for (int mt=0;mt<3;mt++){
    #pragma unroll
    for (int r=0;r<4;r++) dotp[mt][r] = 0.f;
    #pragma unroll
    for (int nt=0;nt<4;nt++){
      #pragma unroll
      for (int r=0;r<4;r++){
        float s = silu_f(acc2[mt][nt][r] + bb2[nt]);
        acc2[mt][nt][r] = s;
        dotp[mt][r] += s*aw[nt];
      }
    }
  }
  #pragma unroll
  for (int off=1; off<16; off<<=1){
    #pragma unroll
    for (int mt=0;mt<3;mt++)
    #pragma unroll
    for (int r=0;r<4;r++)
      dotp[mt][r] += __shfl_xor(dotp[mt][r], off);
  }
  if (nl == 0){
    #pragma unroll
    for (int mt=0;mt<3;mt++)
    #pragma unroll
    for (int r=0;r<4;r++)
      sDot[mt*16 + quad*4 + r][ng] = dotp[mt][r];
  }
  __syncthreads();
  if (tid < 48) sSig[tid] = sigm_f(sDot[tid][0]+sDot[tid][1]+sDot[tid][2]+sDot[tid][3] + attB[l]);
  __syncthreads();
  float sgv[3][4];
  #pragma unroll
  for (int mt=0;mt<3;mt++)
  #pragma unroll
  for (int r=0;r<4;r++)
    sgv[mt][r] = sSig[mt*16 + quad*4 + r];
  #pragma unroll
  for (int nt=0;nt<4;nt++){
    float a = 0.f;
    #pragma unroll
    for (int mt=0;mt<3;mt++)
    #pragma unroll
    for (int r=0;r<4;r++)
      a += acc2[mt][nt][r]*sgv[mt][r];
    a += __shfl_xor(a, 16);
    a += __shfl_xor(a, 32);
    if (quad == 0) agg_bf[(size_t)row*HID + ng*64 + nt*16 + nl] = f2b(a*0.2f);
  }
}

// ---- node MLP + residual + fused QC/QE + fused RC/RE + final outh ----
// grid 256 (1 block/CU), 512 threads (2 waves/SIMD). A-operand staged
// directly from f32 h (f2b == stored-bf16 bits); h_bf round-trip deleted
// (-9.4 MB HBM/launch).
__global__ __launch_bounds__(512,1) void k_node(
    float* __restrict__ h,
    const u16* __restrict__ agg_bf,
    const u16* __restrict__ W1p, const float* __restrict__ B1,
    const u16* __restrict__ W2p, const float* __restrict__ B2,
    const u16* __restrict__ cWab, u16* __restrict__ QbC, float* __restrict__ RC,
    const u16* __restrict__ eWabN, u16* __restrict__ QbE, float* __restrict__ RE, int doE,
    const u16* __restrict__ WoutP, const float* __restrict__ bout,
    float* __restrict__ outH, int doOut, int l)
{
  __shared__ __align__(16) u16 sA[48*520];
  __shared__ __align__(16) u16 sU[48*264];
  u16* sH = sA;
  int blk=blockIdx.x, tid=threadIdx.x;
  int lane=tid&63, wv=tid>>6, quad=lane>>4, nl=lane&15;
  int base = blk*36;
  // stage h (f32 -> bf16, bit-identical to old h_bf) into first 256 cols
  for (int t=tid; t<48*64; t+=512){
    int i=t>>6, s=t&63;
    unsigned int lo, hi;
    if (i < 36){
      float4 hv = ((const float4*)(h + (size_t)(base+i)*HID))[s];
      lo = (unsigned int)f2b(hv.x) | ((unsigned int)f2b(hv.y) << 16);
      hi = (unsigned int)f2b(hv.z) | ((unsigned int)f2b(hv.w) << 16);
    } else { lo = 0u; hi = 0u; }
    uint2 ov; ov.x = lo; ov.y = hi;
    *(uint2*)(sA + i*520 + s*4) = ov;
  }
  // stage agg (bf16) into cols 256..511; pad rows zero
  for (int t=tid; t<48*32; t+=512){
    int i=t>>5, q=t&31;
    uint4 v;
    int node = base+i;
    if (i < 36 && node < N_LIGC) v = ((const uint4*)(agg_bf + (size_t)node*HID))[q];
    else { v.x=0u; v.y=0u; v.z=0u; v.w=0u; }
    *(uint4*)(sA + i*520 + 256 + q*8) = v;
  }
  __syncthreads();
  f32x4 zero4 = {0.f,0.f,0.f,0.f};
  f32x4 acc[3][2];
  #pragma unroll
  for (int i=0;i<3;i++){ acc[i][0]=zero4; acc[i][1]=zero4; }
  const u16* Wp = W1p + (size_t)l*512*HID;
  #pragma unroll 2
  for (int k0=0;k0<16;k0++){
    bf16x8 a0 = *(const bf16x8*)(sA + (0*16+nl)*520 + k0*32 + quad*8);
    bf16x8 a1 = *(const bf16x8*)(sA + (1*16+nl)*520 + k0*32 + quad*8);
    bf16x8 a2 = *(const bf16x8*)(sA + (2*16+nl)*520 + k0*32 + quad*8);
    const u16* wb = Wp + ((size_t)(k0*16 + wv*2)*64 + lane)*8;
    bf16x8 b0 = *(const bf16x8*)(wb);
    bf16x8 b1 = *(const bf16x8*)(wb + 512);
    acc[0][0]=__builtin_amdgcn_mfma_f32_16x16x32_bf16(a0,b0,acc[0][0],0,0,0);
    acc[0][1]=__builtin_amdgcn_mfma_f32_16x16x32_bf16(a0,b1,acc[0][1],0,0,0);
    acc[1][0]=__builtin_amdgcn_mfma_f32_16x16x32_bf16(a1,b0,acc[1][0],0,0,0);
    acc[1][1]=__builtin_amdgcn_mfma_f32_16x16x32_bf16(a1,b1,acc[1][1],0,0,0);
    acc[2][0]=__builtin_amdgcn_mfma_f32_16x16x32_bf16(a2,b0,acc[2][0],0,0,0);
    acc[2][1]=__builtin_amdgcn_mfma_f32_16x16x32_bf16(a2,b1,acc[2][1],0,0,0);
  }
  #pragma unroll
  for (int mt=0;mt<3;mt++)
  #pragma unroll
  for (int nt=0;nt<2;nt++){
    int n = wv*32 + nt*16 + nl;
    float bb = B1[l*HID + n];
    #pragma unroll
    for (int r=0;r<4;r++){
      int m = mt*16 + quad*4 + r;
      sU[m*264 + n] = f2b(silu_f(acc[mt][nt][r] + bb));
    }
  }
  __syncthreads();
  f32x4 acc2[3][2];
  #pragma unroll
  for (int i=0;i<3;i++){ acc2[i][0]=zero4; acc2[i][1]=zero4; }
  const u16* W2 = W2p + (size_t)l*HID*HID;
  #pragma unroll 2
  for (int k0=0;k0<8;k0++){
    bf16x8 a0 = *(const bf16x8*)(sU + (0*16+nl)*264 + k0*32 + quad*8);
    bf16x8 a1 = *(const bf16x8*)(sU + (1*16+nl)*264 + k0*32 + quad*8);
    bf16x8 a2 = *(const bf16x8*)(sU + (2*16+nl)*264 + k0*32 + quad*8);
    const u16* wb = W2 + ((size_t)(k0*16 + wv*2)*64 + lane)*8;
    bf16x8 b0 = *(const bf16x8*)(wb);
    bf16x8 b1 = *(const bf16x8*)(wb + 512);
    acc2[0][0]=__builtin_amdgcn_mfma_f32_16x16x32_bf16(a0,b0,acc2[0][0],0,0,0);
    acc2[0][1]=__builtin_amdgcn_mfma_f32_16x16x32_bf16(a0,b1,acc2[0][1],0,0,0);
    acc2[1][0]=__builtin_amdgcn_mfma_f32_16x16x32_bf16(a1,b0,acc2[1][0],0,0,0);
    acc2[1][1]=__builtin_amdgcn_mfma_f32_16x16x32_bf16(a1,b1,acc2[1][1],0,0,0);
    acc2[2][0]=__builtin_amdgcn_mfma_f32_16x16x32_bf16(a2,b0,acc2[2][0],0,0,0);
    acc2[2][1]=__builtin_amdgcn_mfma_f32_16x16x32_bf16(a2,b1,acc2[2][1],0,0,0);
  }
  #pragma unroll
  for (int mt=0;mt<3;mt++)
  #pragma unroll
  for (int nt=0;nt<2;nt++){
    int n = wv*32 + nt*16 + nl;
    float bb = B2[l*HID + n];
    #pragma unroll
    for (int r=0;r<4;r++){
      int m = mt*16 + quad*4 + r;
      if (m < 36){
        size_t idx = (size_t)(base+m)*HID + n;
        float v = h[idx] + acc2[mt][nt][r] + bb;
        h[idx] = v;
        sH[m*264 + n] = f2b(v);
      } else {
        sH[m*264 + n] = 0;
      }
    }
  }
  __syncthreads();

  int isLig = (base < N_LIGC);
  const u16* Wl = cWab + (size_t)l*512*HID;
  // ---- fused QC+QE: one A-pass, dual B ----
  {
    f32x4 qc[3][2], qe[3][2];
    #pragma unroll
    for (int i=0;i<3;i++){ qc[i][0]=zero4; qc[i][1]=zero4; qe[i][0]=zero4; qe[i][1]=zero4; }
    #pragma unroll 2
    for (int k0=0;k0<8;k0++){
      bf16x8 a0 = *(const bf16x8*)(sH + (0*16+nl)*264 + k0*32 + quad*8);
      bf16x8 a1 = *(const bf16x8*)(sH + (1*16+nl)*264 + k0*32 + quad*8);
      bf16x8 a2 = *(const bf16x8*)(sH + (2*16+nl)*264 + k0*32 + quad*8);
      const u16* wbC = Wl    + ((size_t)((k0+8)*16 + wv*2)*64 + lane)*8;
      const u16* wbE = eWabN + ((size_t)((k0+8)*16 + wv*2)*64 + lane)*8;
      bf16x8 c0 = *(const bf16x8*)(wbC);
      bf16x8 c1 = *(const bf16x8*)(wbC + 512);
      bf16x8 e0 = *(const bf16x8*)(wbE);
      bf16x8 e1 = *(const bf16x8*)(wbE + 512);
      qc[0][0]=__builtin_amdgcn_mfma_f32_16x16x32_bf16(a0,c0,qc[0][0],0,0,0);
      qc[0][1]=__builtin_amdgcn_mfma_f32_16x16x32_bf16(a0,c1,qc[0][1],0,0,0);
      qc[1][0]=__builtin_amdgcn_mfma_f32_16x16x32_bf16(a1,c0,qc[1][0],0,0,0);
      qc[1][1]=__builtin_amdgcn_mfma_f32_16x16x32_bf16(a1,c1,qc[1][1],0,0,0);
      qc[2][0]=__builtin_amdgcn_mfma_f32_16x16x32_bf16(a2,c0,qc[2][0],0,0,0);
      qc[2][1]=__builtin_amdgcn_mfma_f32_16x16x32_bf16(a2,c1,qc[2][1],0,0,0);
      qe[0][0]=__builtin_amdgcn_mfma_f32_16x16x32_bf16(a0,e0,qe[0][0],0,0,0);
      qe[0][1]=__builtin_amdgcn_mfma_f32_16x16x32_bf16(a0,e1,qe[0][1],0,0,0);
      qe[1][0]=__builtin_amdgcn_mfma_f32_16x16x32_bf16(a1,e0,qe[1][0],0,0,0);
      qe[1][1]=__builtin_amdgcn_mfma_f32_16x16x32_bf16(a1,e1,qe[1][1],0,0,0);
      qe[2][0]=__builtin_amdgcn_mfma_f32_16x16x32_bf16(a2,e0,qe[2][0],0,0,0);
      qe[2][1]=__builtin_amdgcn_mfma_f32_16x16x32_bf16(a2,e1,qe[2][1],0,0,0);
    }
    #pragma unroll
    for (int mt=0;mt<3;mt++)
    #pragma unroll
    for (int nt=0;nt<2;nt++){
      int n = wv*32 + nt*16 + nl;
      #pragma unroll
      for (int r=0;r<4;r++){
        int m = mt*16 + quad*4 + r;
        if (m < 36) QbC[(size_t)(base+m)*HID + n] = f2b(qc[mt][nt][r]);
      }
    }
    if (doE){
      #pragma unroll
      for (int mt=0;mt<3;mt++)
      #pragma unroll
      for (int nt=0;nt<2;nt++){
        int n = wv*32 + nt*16 + nl;
        #pragma unroll
        for (int r=0;r<4;r++){
          int m = mt*16 + quad*4 + r;
          if (m < 36) QbE[(size_t)(base+m)*HID + n] = f2b(qe[mt][nt][r]);
        }
      }
    }
  }
  // ---- fused RC+RE (lig blocks only): one A-pass, dual B ----
  if (isLig){
    f32x4 rc[3][2], re[3][2];
    #pragma unroll
    for (int i=0;i<3;i++){ rc[i][0]=zero4; rc[i][1]=zero4; re[i][0]=zero4; re[i][1]=zero4; }
    #pragma unroll 2
    for (int k0=0;k0<8;k0++){
      bf16x8 a0 = *(const bf16x8*)(sH + (0*16+nl)*264 + k0*32 + quad*8);
      bf16x8 a1 = *(const bf16x8*)(sH + (1*16+nl)*264 + k0*32 + quad*8);
      bf16x8 a2 = *(const bf16x8*)(sH + (2*16+nl)*264 + k0*32 + quad*8);
      const u16* wbC = Wl    + ((size_t)(k0*16 + wv*2)*64 + lane)*8;
      const u16* wbE = eWabN + ((size_t)(k0*16 + wv*2)*64 + lane)*8;
      bf16x8 c0 = *(const bf16x8*)(wbC);
      bf16x8 c1 = *(const bf16x8*)(wbC + 512);
      bf16x8 e0 = *(const bf16x8*)(wbE);
      bf16x8 e1 = *(const bf16x8*)(wbE + 512);
      rc[0][0]=__builtin_amdgcn_mfma_f32_16x16x32_bf16(a0,c0,rc[0][0],0,0,0);
      rc[0][1]=__builtin_amdgcn_mfma_f32_16x16x32_bf16(a0,c1,rc[0][1],0,0,0);
      rc[1][0]=__builtin_amdgcn_mfma_f32_16x16x32_bf16(a1,c0,rc[1][0],0,0,0);
      rc[1][1]=__builtin_amdgcn_mfma_f32_16x16x32_bf16(a1,c1,rc[1][1],0,0,0);
      rc[2][0]=__builtin_amdgcn_mfma_f32_16x16x32_bf16(a2,c0,rc[2][0],0,0,0);
      rc[2][1]=__builtin_amdgcn_mfma_f32_16x16x32_bf16(a2,c1,rc[2][1],0,0,0);
      re[0][0]=__builtin_amdgcn_mfma_f32_16x16x32_bf16(a0,e0,re[0][0],0,0,0);
      re[0][1]=__builtin_amdgcn_mfma_f32_16x16x32_bf16(a0,e1,re[0][1],0,0,0);
      re[1][0]=__builtin_amdgcn_mfma_f32_16x16x32_bf16(a1,e0,re[1][0],0,0,0);
      re[1][1]=__builtin_amdgcn_mfma_f32_16x16x32_bf16(a1,e1,re[1][1],0,0,0);
      re[2][0]=__builtin_amdgcn_mfma_f32_16x16x32_bf16(a2,e0,re[2][0],0,0,0);
      re[2][1]=__builtin_amdgcn_mfma_f32_16x16x32_bf16(a2,e1,re[2][1],0,0,0);
    }
    #pragma unroll
    for (int mt=0;mt<3;mt++)
    #pragma unroll
    for (int nt=0;nt<2;nt++){
      int n = wv*32 + nt*16 + nl;
      #pragma unroll
      for (int r=0;r<4;r++){
        int m = mt*16 + quad*4 + r;
        int node = base + m;
        if (m < 36 && node < N_LIGC) RC[(size_t)node*HID + n] = rc[mt][nt][r];
      }
    }
    if (doE){
      #pragma unroll
      for (int mt=0;mt<3;mt++)
      #pragma unroll
      for (int nt=0;nt<2;nt++){
        int n = wv*32 + nt*16 + nl;
        #pragma unroll
        for (int r=0;r<4;r++){
          int m = mt*16 + quad*4 + r;
          int node = base + m;
          if (m < 36 && node < N_LIGC) RE[(size_t)node*HID + n] = re[mt][nt][r];
        }
      }
    }
  }
  if (doOut && isLig && wv < 2){
    int ntw = wv;
    f32x4 o[3]; o[0]=zero4; o[1]=zero4; o[2]=zero4;
    #pragma unroll 2
    for (int k0=0;k0<8;k0++){
      bf16x8 b = *(const bf16x8*)(WoutP + ((size_t)(k0*2 + ntw)*64 + lane)*8);
      #pragma unroll
      for (int mt=0;mt<3;mt++){
        bf16x8 a = *(const bf16x8*)(sH + (mt*16+nl)*264 + k0*32 + quad*8);
        o[mt] = __builtin_amdgcn_mfma_f32_16x16x32_bf16(a,b,o[mt],0,0,0);
      }
    }
    int n = ntw*16 + nl;
    float bb = bout[n];
    #pragma unroll
    for (int mt=0;mt<3;mt++)
    #pragma unroll
    for (int r=0;r<4;r++){
      int m = mt*16 + quad*4 + r;
      int node = base + m;
      if (m < 36 && node < N_LIGC)
        outH[(size_t)node*32 + n] = o[mt][r] + bb;
    }
  }
}

// ---- coord combine (48 edges/block, grid 1024) ----
__global__ __launch_bounds__(256,4) void k_comb_coord(
    const u16* __restrict__ Qb, const float* __restrict__ R,
    const float* __restrict__ xc, float* __restrict__ xn,
    const int* __restrict__ colIdx, const u16* __restrict__ emb0,
    const u16* __restrict__ W1cP, const float* __restrict__ B1,
    const u16* __restrict__ W2p, const float* __restrict__ B2,
    const float* __restrict__ cW3,
    const float* __restrict__ posw, float* __restrict__ outX, int doOut, int l)
{
  __shared__ __align__(16) u16 sQ[48*264];   // Q gather, then M1 in place
  __shared__ __align__(16) u16 sEA[48*40];
  __shared__ float sR[256];
  __shared__ int sCol[48];
  __shared__ float sD[48];
  __shared__ float sCd[48*3];
  __shared__ float sS[48];
  __shared__ float sDot[48][4];

  int row = blockIdx.x, tid = threadIdx.x;
  int lane = tid & 63, ng = tid >> 6;
  int quad = lane >> 4, nl = lane & 15;

  if (tid < 48) sCol[tid] = colIdx[(size_t)row*KNN + tid];
  sR[tid] = R[(size_t)row*HID + tid];
  __syncthreads();
  for (int t = tid; t < 48*32; t += 256){
    int e = t >> 5, q = t & 31;
    uint4 v = ((const uint4*)(Qb + (size_t)sCol[e]*HID))[q];
    *(uint4*)(sQ + e*264 + q*8) = v;
  }
  if (tid < 48){
    int cg = sCol[tid];
    float dx = xc[row*3+0]-xc[cg*3+0];
    float dy = xc[row*3+1]-xc[cg*3+1];
    float dz = xc[row*3+2]-xc[cg*3+2];
    float d = sqrtf(dx*dx+dy*dy+dz*dz + 1e-8f);
    sD[tid] = d;
    float rden = __builtin_amdgcn_rcpf(d + 1.0f);
    sCd[tid*3+0]=dx*rden; sCd[tid*3+1]=dy*rden; sCd[tid*3+2]=dz*rden;
    const unsigned int* ep = (const unsigned int*)(emb0 + ((size_t)row*KNN + tid)*12);
    unsigned int* dd = (unsigned int*)(sEA + tid*40 + 12);
    #pragma unroll
    for (int i=0;i<6;i++) dd[i] = ep[i];
    u16* ea = sEA + tid*40;
    #pragma unroll
    for (int i=24;i<32;i++) ea[i] = 0;
  }
  __syncthreads();
  for (int t=tid; t<288; t+=256){
    int e = t/6, i = t - 6*e;
    float fr = 0.41887903f * (float)(1 << (2*i));
    float x = sD[e]*fr;
    u16* ea = sEA + e*40;
    ea[i]   = f2b(__sinf(x));
    ea[6+i] = f2b(__cosf(x));
  }
  __syncthreads();

  f32x4 zero4 = {0.f,0.f,0.f,0.f};
  f32x4 acc[3][4];
  #pragma unroll
  for (int i=0;i<3;i++){ acc[i][0]=zero4; acc[i][1]=zero4; acc[i][2]=zero4; acc[i][3]=zero4; }
  {
    const u16* Wc = W1cP + (size_t)l*32*HID;
    const u16* wb = Wc + ((size_t)(ng*4)*64 + lane)*8;
    bf16x8 b0 = *(const bf16x8*)(wb);
    bf16x8 b1 = *(const bf16x8*)(wb + 512);
    bf16x8 b2 = *(const bf16x8*)(wb + 1024);
    bf16x8 b3 = *(const bf16x8*)(wb + 1536);
    bf16x8 a0 = *(const bf16x8*)(sEA + (0*16+nl)*40 + quad*8);
    bf16x8 a1 = *(const bf16x8*)(sEA + (1*16+nl)*40 + quad*8);
    bf16x8 a2 = *(const bf16x8*)(sEA + (2*16+nl)*40 + quad*8);
    acc[0][0]=__builtin_amdgcn_mfma_f32_16x16x32_bf16(a0,b0,acc[0][0],0,0,0);
    acc[0][1]=__builtin_amdgcn_mfma_f32_16x16x32_bf16(a0,b1,acc[0][1],0,0,0);
    acc[0][2]=__builtin_amdgcn_mfma_f32_16x16x32_bf16(a0,b2,acc[0][2],0,0,0);
    acc[0][3]=__builtin_amdgcn_mfma_f32_16x16x32_bf16(a0,b3,acc[0][3],0,0,0);
    acc[1][0]=__builtin_amdgcn_mfma_f32_16x16x32_bf16(a1,b0,acc[1][0],0,0,0);
    acc[1][1]=__builtin_amdgcn_mfma_f32_16x16x32_bf16(a1,b1,acc[1][1],0,0,0);
    acc[1][2]=__builtin_amdgcn_mfma_f32_16x16x32_bf16(a1,b2,acc[1][2],0,0,0);
    acc[1][3]=__builtin_amdgcn_mfma_f32_16x16x32_bf16(a1,b3,acc[1][3],0,0,0);
    acc[2][0]=__builtin_amdgcn_mfma_f32_16x16x32_bf16(a2,b0,acc[2][0],0,0,0);
    acc[2][1]=__builtin_amdgcn_mfma_f32_16x16x32_bf16(a2,b1,acc[2][1],0,0,0);
    acc[2][2]=__builtin_amdgcn_mfma_f32_16x16x32_bf16(a2,b2,acc[2][2],0,0,0);
    acc[2][3]=__builtin_amdgcn_mfma_f32_16x16x32_bf16(a2,b3,acc[2][3],0,0,0);
  }
  // in-place M1 epilogue (per-thread RMW ownership; A operand was in sEA)
  #pragma unroll
  for (int mt=0;mt<3;mt++)
  #pragma unroll
  for (int nt=0;nt<4;nt++){
    int n = ng*64 + nt*16 + nl;
    float bb = B1[l*HID + n] + sR[n];
    #pragma unroll
    for (int r=0;r<4;r++){
      int m = mt*16 + quad*4 + r;
      float v = acc[mt][nt][r] + bb + b2f(sQ[m*264 + n]);
      sQ[m*264 + n] = f2b(silu_f(v));
    }
  }
  __syncthreads();

  f32x4 acc2[3][4];
  #pragma unroll
  for (int i=0;i<3;i++){ acc2[i][0]=zero4; acc2[i][1]=zero4; acc2[i][2]=zero4; acc2[i][3]=zero4; }
  const u16* W2 = W2p + (size_t)l*HID*HID;
  #pragma unroll 2
  for (int k0=0;k0<8;k0++){
    bf16x8 a0 = *(const bf16x8*)(sQ + (0*16+nl)*264 + k0*32 + quad*8);
    bf16x8 a1 = *(const bf16x8*)(sQ + (1*16+nl)*264 + k0*32 + quad*8);
    bf16x8 a2 = *(const bf16x8*)(sQ + (2*16+nl)*264 + k0*32 + quad*8);
    const u16* wb = W2 + ((size_t)(k0*16 + ng*4)*64 + lane)*8;
    bf16x8 b0 = *(const bf16x8*)(wb);
    bf16x8 b1 = *(const bf16x8*)(wb + 512);
    bf16x8 b2 = *(const bf16x8*)(wb + 1024);
    bf16x8 b3 = *(const bf16x8*)(wb + 1536);
    acc2[0][0]=__builtin_amdgcn_mfma_f32_16x16x32_bf16(a0,b0,acc2[0][0],0,0,0);
    acc2[0][1]=__builtin_amdgcn_mfma_f32_16x16x32_bf16(a0,b1,acc2[0][1],0,0,0);
    acc2[0][2]=__builtin_amdgcn_mfma_f32_16x16x32_bf16(a0,b2,acc2[0][2],0,0,0);
    acc2[0][3]=__builtin_amdgcn_mfma_f32_16x16x32_bf16(a0,b3,acc2[0][3],0,0,0);
    acc2[1][0]=__builtin_amdgcn_mfma_f32_16x16x32_bf16(a1,b0,acc2[1][0],0,0,0);
    acc2[1][1]=__builtin_amdgcn_mfma_f32_16x16x32_bf16(a1,b1,acc2[1][1],0,0,0);
    acc2[1][2]=__builtin_amdgcn_mfma_f32_16x16x32_bf16(a1,b2,acc2[1][2],0,0,0);
    acc2[1][3]=__builtin_amdgcn_mfma_f32_16x16x32_bf16(a1,b3,acc2[1][3],0,0,0);
    acc2[2][0]=__builtin_amdgcn_mfma_f32_16x16x32_bf16(a2,b0,acc2[2][0],0,0,0);
    acc2[2][1]=__builtin_amdgcn_mfma_f32_16x16x32_bf16(a2,b1,acc2[2][1],0,0,0);
    acc2[2][2]=__builtin_amdgcn_mfma_f32_16x16x32_bf16(a2,b2,acc2[2][2],0,0,0);
    acc2[2][3]=__builtin_amdgcn_mfma_f32_16x16x32_bf16(a2,b3,acc2[2][3],0,0,0);
  }
  // register epilogue: silu + dot with cW3, shfl-reduce over nl
  float cw[4], bb2[4];
  #pragma unroll
  for (int nt=0;nt<4;nt++){
    int n = ng*64 + nt*16 + nl;
    cw[nt]  = cW3[l*HID + n];
    bb2[nt] = B2[l*HID + n];
  }
  float dotp[3][4];
  #pragma unroll
  for (int mt=0;mt<3;mt++){
    #pragma unroll
    for (int r=0;r<4;r++) dotp[mt][r] = 0.f;
    #pragma unroll
    for (int nt=0;nt<4;nt++){
      #pragma unroll
      for (int r=0;r<4;r++){
        float s = silu_f(acc2[mt][nt][r] + bb2[nt]);
        dotp[mt][r] += s*cw[nt];
      }
    }
  }
  #pragma unroll
  for (int off=1; off<16; off<<=1){
    #pragma unroll
    for (int mt=0;mt<3;mt++)
    #pragma unroll
    for (int r=0;r<4;r++)
      dotp[mt][r] += __shfl_xor(dotp[mt][r], off);
  }
  if (nl == 0){
    #pragma unroll
    for (int mt=0;mt<3;mt++)
    #pragma unroll
    for (int r=0;r<4;r++)
      sDot[mt*16 + quad*4 + r][ng] = dotp[mt][r];
  }
  __syncthreads();
  if (tid < 48) sS[tid] = sDot[tid][0]+sDot[tid][1]+sDot[tid][2]+sDot[tid][3];
  __syncthreads();
  if (tid < 3){
    float u = 0.f;
    #pragma unroll 4
    for (int e=0;e<48;e++) u += sCd[e*3+tid]*sS[e];
    float nv = xc[row*3+tid] + u*0.2f;
    xn[row*3+tid] = nv;
    if (doOut) outX[row*3+tid] = nv*posw[0];
  }
}

extern "C" void kernel_launch(void* const* d_in, const int* in_sizes, int n_in,
                              void* d_out, int out_size, void* d_ws, size_t ws_size,
                              hipStream_t stream)
{
  const float* protPos = (const float*)d_in[0];
  const int*   protEle = (const int*)d_in[1];
  const int*   protAA  = (const int*)d_in[2];
  const int*   protBB  = (const int*)d_in[3];
  const float* XtPos   = (const float*)d_in[4];
  const float* XtFeat  = (const float*)d_in[5];
  const int*   tArr    = (const int*)d_in[6];
  const float* WtTime  = (const float*)d_in[7];
  const float* Wele    = (const float*)d_in[8];
  const float* Waa     = (const float*)d_in[9];
  const float* Wbb     = (const float*)d_in[10];
  const float* Win     = (const float*)d_in[11];
  const float* bin     = (const float*)d_in[12];
  const float* Wout    = (const float*)d_in[13];
  const float* bout    = (const float*)d_in[14];
  const float* eW1     = (const float*)d_in[15];
  const float* eB1     = (const float*)d_in[16];
  const float* eW2     = (const float*)d_in[17];
  const float* eB2     = (const float*)d_in[18];
  const float* attW    = (const float*)d_in[19];
  const float* attB    = (const float*)d_in[20];
  const float* nW1     = (const float*)d_in[21];
  const float* nB1     = (const float*)d_in[22];
  const float* nW2     = (const float*)d_in[23];
  const float* nB2     = (const float*)d_in[24];
  const float* cW1     = (const float*)d_in[25];
  const float* cB1     = (const float*)d_in[26];
  const float* cW2     = (const float*)d_in[27];
  const float* cB2     = (const float*)d_in[28];
  const float* cW3     = (const float*)d_in[29];
  const float* posw    = (const float*)d_in[30];

  float* fp = (float*)d_ws;
  float* X0   = fp;               fp += NTOT*3;
  float* X1   = fp;               fp += NTOT*3;
  float* h    = fp;               fp += (size_t)NTOT*HID;
  float* RC   = fp;               fp += (size_t)N_LIGC*HID;
  float* RE   = fp;               fp += (size_t)N_LIGC*HID;
  int*   col  = (int*)fp;         fp += ETOT;
  u16*   up   = (u16*)fp;
  u16* emb0   = up;               up += (size_t)ETOT*12;
  u16* h_bf   = up;               up += (size_t)NTOT*HID;
  u16* agg_bf = up;               up += (size_t)N_LIGC*HID;
  u16* QbE    = up;               up += (size_t)NTOT*HID;
  u16* QbC    = up;               up += (size_t)NTOT*HID;
  u16* eW1abP = up;               up += (size_t)DEPTHC*512*HID;
  u16* eW1cP  = up;               up += (size_t)DEPTHC*32*HID;
  u16* eW2p   = up;               up += (size_t)DEPTHC*HID*HID;
  u16* nW1p   = up;               up += (size_t)DEPTHC*512*HID;
  u16* nW2p   = up;               up += (size_t)DEPTHC*HID*HID;
  u16* cW1abP = up;               up += (size_t)DEPTHC*512*HID;
  u16* cW1cP  = up;               up += (size_t)DEPTHC*32*HID;
  u16* cW2p   = up;               up += (size_t)DEPTHC*HID*HID;
  u16* WoutP  = up;               up += (size_t)256*32;

  k_prep<<<PACK_BLKS + NTOT/8,256,0,stream>>>(eW1,eW2,nW1,nW2,cW1,cW2,Wout,
      eW1abP,eW1cP,eW2p,nW1p,nW2p,cW1abP,cW1cP,cW2p,WoutP,
      protPos,protEle,protAA,protBB,XtPos,XtFeat,
      tArr,WtTime,Wele,Waa,Wbb,Win,bin,X0,X1,h,h_bf);
  k_knn_pq<<<256 + N_LIGC,512,0,stream>>>(X0,col,emb0,h_bf,eW1abP,RE,QbE);

  float* xc = X0; float* xn = X1;
  float* outF = (float*)d_out;
  for (int l=0;l<DEPTHC;l++){
    k_comb_edge<<<N_LIGC,256,0,stream>>>(QbE,RE,xc,col,emb0,eW1cP,eB1,eW2p,eB2,attW,attB,agg_bf,l);
    const u16* eNext = eW1abP + (size_t)((l+1)%DEPTHC)*512*HID;
    k_node<<<256,512,0,stream>>>(h,agg_bf,nW1p,nB1,nW2p,nB2,
        cW1abP,QbC,RC, eNext,QbE,RE,(l<DEPTHC-1)?1:0,
        WoutP,bout, outF+3072, (l==DEPTHC-1)?1:0, l);
    k_comb_coord<<<N_LIGC,256,0,stream>>>(QbC,RC,xc,xn,col,emb0,cW1cP,cB1,cW2p,cB2,cW3,
        posw, outF, (l==DEPTHC-1)?1:0, l);
    float* t2=xc; xc=xn; xn=t2;
  }
}

// Round 11
// 456.396 us; speedup vs baseline: 1.0507x; 1.0478x over previous
//
#include <hip/hip_runtime.h>
#include <hip/hip_bf16.h>
#include <math.h>

#define N_LIGC 1024
#define NTOT 9216
#define KNN 48
#define HID 256
#define DEPTHC 5
#define ETOT (N_LIGC*KNN)
#define KBINS 4096
#define PACK_BLKS 1484

typedef unsigned short u16;
typedef __attribute__((ext_vector_type(8))) short bf16x8;
typedef __attribute__((ext_vector_type(4))) float f32x4;

__device__ __forceinline__ float freq_f(int i){
  double p = (double)(1 << (2*i));
  return (float)((2.0*3.14159265358979323846)*p/15.0);
}
// fast silu/sigmoid: native exp + single v_rcp_f32 (avoids IEEE div sequence)
__device__ __forceinline__ float silu_f(float v){
  return v*__builtin_amdgcn_rcpf(1.0f+__expf(-v));
}
__device__ __forceinline__ float sigm_f(float v){
  return __builtin_amdgcn_rcpf(1.0f+__expf(-v));
}
// branchless RNE float->bf16
__device__ __forceinline__ u16 f2b(float f){
  unsigned int u = __float_as_uint(f);
  return (u16)((u + 0x7fffu + ((u>>16)&1u)) >> 16);
}
__device__ __forceinline__ float b2f(u16 u){
  union { unsigned int i; float f; } c; c.i = ((unsigned int)u)<<16; return c.f;
}
// precise RNE (for weight packing, matches __float2bfloat16)
__device__ __forceinline__ u16 f2b_p(float f){
  union { __hip_bfloat16 h; u16 u; } c; c.h = __float2bfloat16(f); return c.u;
}

// ---- pack fp32 [L][srcK][N] rows [kOff,kOff+Keff) -> bf16 B-frag layout
__device__ __forceinline__ void pack_one(const float* __restrict__ src,
    u16* __restrict__ dst, int srcK, int kOff, int Keff, int Kp, int N, int idx)
{
  int lane = idx & 63;
  int rest = idx >> 6;
  int Nt = N >> 4;
  int n0 = rest % Nt;
  int rest2 = rest / Nt;
  int Kt = Kp >> 5;
  int k0 = rest2 % Kt;
  int layer = rest2 / Kt;
  int kq = lane >> 4, nl = lane & 15;
  int kb = k0*32 + kq*8, n = n0*16 + nl;
  u16 o[8];
  #pragma unroll
  for (int j=0;j<8;j++){
    int k = kb + j;
    float v = (k < Keff) ? src[((size_t)layer*srcK + kOff + k)*N + n] : 0.f;
    o[j] = f2b_p(v);
  }
  *(uint4*)(dst + (size_t)idx*8) = *(uint4*)o;
}

// ---- merged: weight pack (blocks 0..1483) + embed/h-init (blocks 1484..) ----
__global__ __launch_bounds__(256) void k_prep(
    const float* eW1, const float* eW2, const float* nW1, const float* nW2,
    const float* cW1, const float* cW2, const float* Wout,
    u16* eW1abP, u16* eW1cP, u16* eW2p, u16* nW1p, u16* nW2p,
    u16* cW1abP, u16* cW1cP, u16* cW2p, u16* WoutP,
    const float* __restrict__ protPos, const int* __restrict__ protEle,
    const int* __restrict__ protAA, const int* __restrict__ protBB,
    const float* __restrict__ XtPos, const float* __restrict__ XtFeat,
    const int* __restrict__ tArr, const float* __restrict__ WtTime,
    const float* __restrict__ Wele, const float* __restrict__ Waa,
    const float* __restrict__ Wbb,
    const float* __restrict__ Win, const float* __restrict__ bin,
    float* __restrict__ X0, float* __restrict__ X1,
    float* __restrict__ h, u16* __restrict__ h_bf)
{
  __shared__ float sF[8*40];
  if (blockIdx.x < PACK_BLKS){
    int idx = blockIdx.x*256 + threadIdx.x;
    if (idx < 81920){ pack_one(eW1, eW1abP, 536, 0,   512, 512, 256, idx); return; } idx -= 81920;
    if (idx < 5120 ){ pack_one(eW1, eW1cP,  536, 512, 24,  32,  256, idx); return; } idx -= 5120;
    if (idx < 40960){ pack_one(eW2, eW2p,   256, 0,   256, 256, 256, idx); return; } idx -= 40960;
    if (idx < 81920){ pack_one(nW1, nW1p,   512, 0,   512, 512, 256, idx); return; } idx -= 81920;
    if (idx < 40960){ pack_one(nW2, nW2p,   256, 0,   256, 256, 256, idx); return; } idx -= 40960;
    if (idx < 81920){ pack_one(cW1, cW1abP, 536, 0,   512, 512, 256, idx); return; } idx -= 81920;
    if (idx < 5120 ){ pack_one(cW1, cW1cP,  536, 512, 24,  32,  256, idx); return; } idx -= 5120;
    if (idx < 40960){ pack_one(cW2, cW2p,   256, 0,   256, 256, 256, idx); return; } idx -= 40960;
    if (idx < 1024 ){ pack_one(Wout, WoutP, 256, 0,   256, 256, 32,  idx); return; }
    return;
  }
  int blk=blockIdx.x - PACK_BLKS, tid=threadIdx.x;
  int n0=blk*8;
  for (int x=tid; x<344; x+=256){
    if (x < 320){
      int n = x/40, k = x%40;
      int node = n0+n;
      float v;
      if (node < N_LIGC){
        if (k < 32) v = XtFeat[node*32+k];
        else        v = WtTime[tArr[node]*8 + (k-32)];
      } else {
        int p = node - N_LIGC;
        if (k < 16)      v = Wele[protEle[p]*16 + k];
        else if (k < 32) v = Waa[protAA[p]*16 + (k-16)];
        else             v = Wbb[protBB[p]*8 + (k-32)];
      }
      sF[n*40+k] = v;
    } else {
      int r = x-320; int n = r/3, c = r%3;
      int node = n0+n;
      float v = (node < N_LIGC) ? XtPos[node*3+c] : protPos[(node-N_LIGC)*3+c];
      X0[node*3+c] = v; X1[node*3+c] = v;
    }
  }
  __syncthreads();
  float acc[8];
  float b=bin[tid];
  #pragma unroll
  for (int n=0;n<8;n++) acc[n]=b;
  for (int k=0;k<40;k++){
    float w=Win[k*HID+tid];
    #pragma unroll
    for (int n=0;n<8;n++) acc[n]+=sF[n*40+k]*w;
  }
  #pragma unroll
  for (int n=0;n<8;n++){
    h[(size_t)(n0+n)*HID+tid]=acc[n];
    h_bf[(size_t)(n0+n)*HID+tid]=f2b_p(acc[n]);
  }
}

// ---- merged KNN + PQ (independent, both depend only on k_prep) ----
// blocks 0..255: pq (512 threads); blocks 256..1279: knn (threads>=256 retire).
__global__ __launch_bounds__(512,1) void k_knn_pq(
    const float* __restrict__ X, int* __restrict__ col, u16* __restrict__ emb0,
    const u16* __restrict__ h_bf, const u16* __restrict__ Wab,
    float* __restrict__ R, u16* __restrict__ Qb)
{
  __shared__ __align__(16) unsigned char smem[25856];
  int tid = threadIdx.x;
  if (blockIdx.x < 256){
    u16* sA = (u16*)smem;
    int blk=blockIdx.x;
    int lane=tid&63, wv=tid>>6, quad=lane>>4, nl=lane&15;
    int base = blk*36;
    for (int t=tid; t<48*32; t+=512){
      int i=t>>5, q=t&31;
      uint4 v;
      if (i < 36) v = ((const uint4*)(h_bf + (size_t)(base+i)*HID))[q];
      else { v.x=0u; v.y=0u; v.z=0u; v.w=0u; }
      *(uint4*)(sA + i*264 + q*8) = v;
    }
    __syncthreads();
    const u16* Wl = Wab;   // l = 0
    f32x4 zero4 = {0.f,0.f,0.f,0.f};
    f32x4 aQ[3][2];
    #pragma unroll
    for (int i=0;i<3;i++){ aQ[i][0]=zero4; aQ[i][1]=zero4; }
    #pragma unroll 2
    for (int k0=0;k0<8;k0++){
      bf16x8 a0 = *(const bf16x8*)(sA + (0*16+nl)*264 + k0*32 + quad*8);
      bf16x8 a1 = *(const bf16x8*)(sA + (1*16+nl)*264 + k0*32 + quad*8);
      bf16x8 a2 = *(const bf16x8*)(sA + (2*16+nl)*264 + k0*32 + quad*8);
      const u16* wb = Wl + ((size_t)((k0+8)*16 + wv*2)*64 + lane)*8;
      bf16x8 b0 = *(const bf16x8*)(wb);
      bf16x8 b1 = *(const bf16x8*)(wb + 512);
      aQ[0][0]=__builtin_amdgcn_mfma_f32_16x16x32_bf16(a0,b0,aQ[0][0],0,0,0);
      aQ[0][1]=__builtin_amdgcn_mfma_f32_16x16x32_bf16(a0,b1,aQ[0][1],0,0,0);
      aQ[1][0]=__builtin_amdgcn_mfma_f32_16x16x32_bf16(a1,b0,aQ[1][0],0,0,0);
      aQ[1][1]=__builtin_amdgcn_mfma_f32_16x16x32_bf16(a1,b1,aQ[1][1],0,0,0);
      aQ[2][0]=__builtin_amdgcn_mfma_f32_16x16x32_bf16(a2,b0,aQ[2][0],0,0,0);
      aQ[2][1]=__builtin_amdgcn_mfma_f32_16x16x32_bf16(a2,b1,aQ[2][1],0,0,0);
    }
    #pragma unroll
    for (int mt=0;mt<3;mt++)
    #pragma unroll
    for (int nt=0;nt<2;nt++){
      int n = wv*32 + nt*16 + nl;
      #pragma unroll
      for (int r=0;r<4;r++){
        int m = mt*16 + quad*4 + r;
        if (m < 36) Qb[(size_t)(base+m)*HID + n] = f2b(aQ[mt][nt][r]);
      }
    }
    if (base < N_LIGC){
      f32x4 aR[3][2];
      #pragma unroll
      for (int i=0;i<3;i++){ aR[i][0]=zero4; aR[i][1]=zero4; }
      #pragma unroll 2
      for (int k0=0;k0<8;k0++){
        bf16x8 a0 = *(const bf16x8*)(sA + (0*16+nl)*264 + k0*32 + quad*8);
        bf16x8 a1 = *(const bf16x8*)(sA + (1*16+nl)*264 + k0*32 + quad*8);
        bf16x8 a2 = *(const bf16x8*)(sA + (2*16+nl)*264 + k0*32 + quad*8);
        const u16* wb = Wl + ((size_t)(k0*16 + wv*2)*64 + lane)*8;
        bf16x8 b0 = *(const bf16x8*)(wb);
        bf16x8 b1 = *(const bf16x8*)(wb + 512);
        aR[0][0]=__builtin_amdgcn_mfma_f32_16x16x32_bf16(a0,b0,aR[0][0],0,0,0);
        aR[0][1]=__builtin_amdgcn_mfma_f32_16x16x32_bf16(a0,b1,aR[0][1],0,0,0);
        aR[1][0]=__builtin_amdgcn_mfma_f32_16x16x32_bf16(a1,b0,aR[1][0],0,0,0);
        aR[1][1]=__builtin_amdgcn_mfma_f32_16x16x32_bf16(a1,b1,aR[1][1],0,0,0);
        aR[2][0]=__builtin_amdgcn_mfma_f32_16x16x32_bf16(a2,b0,aR[2][0],0,0,0);
        aR[2][1]=__builtin_amdgcn_mfma_f32_16x16x32_bf16(a2,b1,aR[2][1],0,0,0);
      }
      #pragma unroll
      for (int mt=0;mt<3;mt++)
      #pragma unroll
      for (int nt=0;nt<2;nt++){
        int n = wv*32 + nt*16 + nl;
        #pragma unroll
        for (int r=0;r<4;r++){
          int m = mt*16 + quad*4 + r;
          int node = base + m;
          if (m < 36 && node < N_LIGC) R[(size_t)node*HID + n] = aR[mt][nt][r];
        }
      }
    }
    return;
  }
  if (tid >= 256) return;
  unsigned int* hist  = (unsigned int*)smem;
  int*          candI = (int*)(smem + 16384);
  float*        candV = (float*)(smem + 20480);
  unsigned int* scanb = (unsigned int*)(smem + 24576);
  float*        selD  = (float*)(smem + 25600);
  int*          sInt  = (int*)(smem + 25792);
  int b = blockIdx.x - 256;
  for (int i=tid;i<KBINS;i+=256) hist[i]=0u;
  if (tid==0){ sInt[3]=0; }
  float px = X[b*3+0], py = X[b*3+1], pz = X[b*3+2];
  __syncthreads();
  float d2v[36];
  float mn = INFINITY;
  #pragma unroll
  for (int j=0;j<36;j++){
    int i = tid + 256*j;
    float dx = __fsub_rn(px, X[i*3+0]);
    float dy = __fsub_rn(py, X[i*3+1]);
    float dz = __fsub_rn(pz, X[i*3+2]);
    float d2 = __fadd_rn(__fadd_rn(__fmul_rn(dx,dx),__fmul_rn(dy,dy)),__fmul_rn(dz,dz));
    if (i==b) d2 = INFINITY;
    d2v[j] = d2;
    mn = fminf(mn, d2);
  }
  {
    unsigned mkey = __float_as_uint(mn) >> 19;
    if (mkey >= KBINS) mkey = KBINS-1;
    atomicAdd(&hist[mkey], 1u);
  }
  __syncthreads();
  unsigned s=0;
  {
    #pragma unroll 4
    for (int k=0;k<16;k++) s += hist[tid*16+k];
    scanb[tid]=s;
  }
  __syncthreads();
  #pragma unroll
  for (int off=1; off<256; off<<=1){
    unsigned v = (tid>=off) ? scanb[tid-off] : 0u;
    __syncthreads();
    scanb[tid] += v;
    __syncthreads();
  }
  {
    unsigned incl = scanb[tid];
    unsigned excl = incl - s;
    if (excl < (unsigned)KNN && incl >= (unsigned)KNN){ sInt[2] = tid; sInt[1] = (int)excl; }
  }
  __syncthreads();
  if (tid==0){
    unsigned c = (unsigned)sInt[1]; int bin = sInt[2]*16;
    for (;;bin++){
      unsigned hh = hist[bin];
      if (c + hh >= (unsigned)KNN) break;
      c += hh;
    }
    sInt[0] = bin;
  }
  __syncthreads();
  int Bp = sInt[0];
  #pragma unroll
  for (int j=0;j<36;j++){
    float d2 = d2v[j];
    int key = (int)(__float_as_uint(d2) >> 19);
    if (key <= Bp){
      int c = atomicAdd(&sInt[3], 1);
      if (c < 1024){ candI[c] = tid + 256*j; candV[c] = d2; }
    }
  }
  __syncthreads();
  {
    int m = sInt[3]; if (m > 1024) m = 1024;
    for (int c = tid; c < m; c += 256){
      float v = candV[c]; int idx = candI[c];
      int rank = 0;
      for (int o = 0; o < m; o++){
        float ov = candV[o];
        if (ov < v || (ov == v && candI[o] < idx)) rank++;
      }
      if (rank < KNN){ col[b*KNN+rank] = idx; selD[rank] = v; }
    }
  }
  __syncthreads();
  if (tid < KNN){
    float d = sqrtf(selD[tid] + 1e-8f);
    int base = (b*KNN+tid)*12;
    #pragma unroll
    for (int i=0;i<6;i++){
      float fr = freq_f(i);
      emb0[base+i]   = f2b_p(sinf(d*fr));
      emb0[base+6+i] = f2b_p(cosf(d*fr));
    }
  }
}

// ---- edge combine (48 edges/block, grid 1024) ----
__global__ __launch_bounds__(256,4) void k_comb_edge(
    const u16* __restrict__ Qb, const float* __restrict__ R,
    const float* __restrict__ xc,
    const int* __restrict__ colIdx, const u16* __restrict__ emb0,
    const u16* __restrict__ W1cP, const float* __restrict__ B1,
    const u16* __restrict__ W2p, const float* __restrict__ B2,
    const float* __restrict__ attW, const float* __restrict__ attB,
    u16* __restrict__ agg_bf, int l)
{
  __shared__ __align__(16) u16 sQ[48*264];   // Q gather, then M1 in place
  __shared__ __align__(16) u16 sEA[48*40];
  __shared__ float sR[256];
  __shared__ int sCol[48];
  __shared__ float sD[48];
  __shared__ float sSig[48];
  __shared__ float sDot[48][4];

  int row = blockIdx.x, tid = threadIdx.x;
  int lane = tid & 63, ng = tid >> 6;
  int quad = lane >> 4, nl = lane & 15;

  if (tid < 48) sCol[tid] = colIdx[(size_t)row*KNN + tid];
  sR[tid] = R[(size_t)row*HID + tid];
  __syncthreads();
  for (int t = tid; t < 48*32; t += 256){
    int e = t >> 5, q = t & 31;
    uint4 v = ((const uint4*)(Qb + (size_t)sCol[e]*HID))[q];
    *(uint4*)(sQ + e*264 + q*8) = v;
  }
  if (tid < 48){
    int cg = sCol[tid];
    float dx = xc[row*3+0]-xc[cg*3+0];
    float dy = xc[row*3+1]-xc[cg*3+1];
    float dz = xc[row*3+2]-xc[cg*3+2];
    float d = sqrtf(dx*dx+dy*dy+dz*dz + 1e-8f);
    sD[tid] = d;
    const unsigned int* ep = (const unsigned int*)(emb0 + ((size_t)row*KNN + tid)*12);
    unsigned int* dd = (unsigned int*)(sEA + tid*40 + 12);
    #pragma unroll
    for (int i=0;i<6;i++) dd[i] = ep[i];
    u16* ea = sEA + tid*40;
    #pragma unroll
    for (int i=24;i<32;i++) ea[i] = 0;
  }
  __syncthreads();
  for (int t=tid; t<288; t+=256){
    int e = t/6, i = t - 6*e;
    float fr = 0.41887903f * (float)(1 << (2*i));
    float x = sD[e]*fr;
    u16* ea = sEA + e*40;
    ea[i]   = f2b(__sinf(x));
    ea[6+i] = f2b(__cosf(x));
  }
  __syncthreads();

  f32x4 zero4 = {0.f,0.f,0.f,0.f};
  f32x4 acc[3][4];
  #pragma unroll
  for (int i=0;i<3;i++){ acc[i][0]=zero4; acc[i][1]=zero4; acc[i][2]=zero4; acc[i][3]=zero4; }
  {
    const u16* Wc = W1cP + (size_t)l*32*HID;
    const u16* wb = Wc + ((size_t)(ng*4)*64 + lane)*8;
    bf16x8 b0 = *(const bf16x8*)(wb);
    bf16x8 b1 = *(const bf16x8*)(wb + 512);
    bf16x8 b2 = *(const bf16x8*)(wb + 1024);
    bf16x8 b3 = *(const bf16x8*)(wb + 1536);
    bf16x8 a0 = *(const bf16x8*)(sEA + (0*16+nl)*40 + quad*8);
    bf16x8 a1 = *(const bf16x8*)(sEA + (1*16+nl)*40 + quad*8);
    bf16x8 a2 = *(const bf16x8*)(sEA + (2*16+nl)*40 + quad*8);
    acc[0][0]=__builtin_amdgcn_mfma_f32_16x16x32_bf16(a0,b0,acc[0][0],0,0,0);
    acc[0][1]=__builtin_amdgcn_mfma_f32_16x16x32_bf16(a0,b1,acc[0][1],0,0,0);
    acc[0][2]=__builtin_amdgcn_mfma_f32_16x16x32_bf16(a0,b2,acc[0][2],0,0,0);
    acc[0][3]=__builtin_amdgcn_mfma_f32_16x16x32_bf16(a0,b3,acc[0][3],0,0,0);
    acc[1][0]=__builtin_amdgcn_mfma_f32_16x16x32_bf16(a1,b0,acc[1][0],0,0,0);
    acc[1][1]=__builtin_amdgcn_mfma_f32_16x16x32_bf16(a1,b1,acc[1][1],0,0,0);
    acc[1][2]=__builtin_amdgcn_mfma_f32_16x16x32_bf16(a1,b2,acc[1][2],0,0,0);
    acc[1][3]=__builtin_amdgcn_mfma_f32_16x16x32_bf16(a1,b3,acc[1][3],0,0,0);
    acc[2][0]=__builtin_amdgcn_mfma_f32_16x16x32_bf16(a2,b0,acc[2][0],0,0,0);
    acc[2][1]=__builtin_amdgcn_mfma_f32_16x16x32_bf16(a2,b1,acc[2][1],0,0,0);
    acc[2][2]=__builtin_amdgcn_mfma_f32_16x16x32_bf16(a2,b2,acc[2][2],0,0,0);
    acc[2][3]=__builtin_amdgcn_mfma_f32_16x16x32_bf16(a2,b3,acc[2][3],0,0,0);
  }
  // in-place M1 epilogue: per-thread RMW ownership; A operand lives in sEA
  #pragma unroll
  for (int mt=0;mt<3;mt++)
  #pragma unroll
  for (int nt=0;nt<4;nt++){
    int n = ng*64 + nt*16 + nl;
    float bb = B1[l*HID + n] + sR[n];
    #pragma unroll
    for (int r=0;r<4;r++){
      int m = mt*16 + quad*4 + r;
      float v = acc[mt][nt][r] + bb + b2f(sQ[m*264 + n]);
      sQ[m*264 + n] = f2b(silu_f(v));
    }
  }
  __syncthreads();

  f32x4 acc2[3][4];
  #pragma unroll
  for (int i=0;i<3;i++){ acc2[i][0]=zero4; acc2[i][1]=zero4; acc2[i][2]=zero4; acc2[i][3]=zero4; }
  const u16* W2 = W2p + (size_t)l*HID*HID;
  #pragma unroll 2
  for (int k0=0;k0<8;k0++){
    bf16x8 a0 = *(const bf16x8*)(sQ + (0*16+nl)*264 + k0*32 + quad*8);
    bf16x8 a1 = *(const bf16x8*)(sQ + (1*16+nl)*264 + k0*32 + quad*8);
    bf16x8 a2 = *(const bf16x8*)(sQ + (2*16+nl)*264 + k0*32 + quad*8);
    const u16* wb = W2 + ((size_t)(k0*16 + ng*4)*64 + lane)*8;
    bf16x8 b0 = *(const bf16x8*)(wb);
    bf16x8 b1 = *(const bf16x8*)(wb + 512);
    bf16x8 b2 = *(const bf16x8*)(wb + 1024);
    bf16x8 b3 = *(const bf16x8*)(wb + 1536);
    acc2[0][0]=__builtin_amdgcn_mfma_f32_16x16x32_bf16(a0,b0,acc2[0][0],0,0,0);
    acc2[0][1]=__builtin_amdgcn_mfma_f32_16x16x32_bf16(a0,b1,acc2[0][1],0,0,0);
    acc2[0][2]=__builtin_amdgcn_mfma_f32_16x16x32_bf16(a0,b2,acc2[0][2],0,0,0);
    acc2[0][3]=__builtin_amdgcn_mfma_f32_16x16x32_bf16(a0,b3,acc2[0][3],0,0,0);
    acc2[1][0]=__builtin_amdgcn_mfma_f32_16x16x32_bf16(a1,b0,acc2[1][0],0,0,0);
    acc2[1][1]=__builtin_amdgcn_mfma_f32_16x16x32_bf16(a1,b1,acc2[1][1],0,0,0);
    acc2[1][2]=__builtin_amdgcn_mfma_f32_16x16x32_bf16(a1,b2,acc2[1][2],0,0,0);
    acc2[1][3]=__builtin_amdgcn_mfma_f32_16x16x32_bf16(a1,b3,acc2[1][3],0,0,0);
    acc2[2][0]=__builtin_amdgcn_mfma_f32_16x16x32_bf16(a2,b0,acc2[2][0],0,0,0);
    acc2[2][1]=__builtin_amdgcn_mfma_f32_16x16x32_bf16(a2,b1,acc2[2][1],0,0,0);
    acc2[2][2]=__builtin_amdgcn_mfma_f32_16x16x32_bf16(a2,b2,acc2[2][2],0,0,0);
    acc2[2][3]=__builtin_amdgcn_mfma_f32_16x16x32_bf16(a2,b3,acc2[2][3],0,0,0);
  }
  // M2 epilogue fully in registers
  float aw[4], bb2[4];
  #pragma unroll
  for (int nt=0;nt<4;nt++){
    int n = ng*64 + nt*16 + nl;
    aw[nt]  = attW[l*HID + n];
    bb2[nt] = B2[l*HID + n];
  }
  float dotp[3][4];
  #pragma unroll
  for (int mt=0;mt<3;mt++){
    #pragma unroll
    for (int r=0;r<4;r++) dotp[mt][r] = 0.f;
    #pragma unroll
    for (int nt=0;nt<4;nt++){
      #pragma unroll
      for (int r=0;r<4;r++){
        float s = silu_f(acc2[mt][nt][r] + bb2[nt]);
        acc2[mt][nt][r] = s;
        dotp[mt][r] += s*aw[nt];
      }
    }
  }
  #pragma unroll
  for (int off=1; off<16; off<<=1){
    #pragma unroll
    for (int mt=0;mt<3;mt++)
    #pragma unroll
    for (int r=0;r<4;r++)
      dotp[mt][r] += __shfl_xor(dotp[mt][r], off);
  }
  if (nl == 0){
    #pragma unroll
    for (int mt=0;mt<3;mt++)
    #pragma unroll
    for (int r=0;r<4;r++)
      sDot[mt*16 + quad*4 + r][ng] = dotp[mt][r];
  }
  __syncthreads();
  if (tid < 48) sSig[tid] = sigm_f(sDot[tid][0]+sDot[tid][1]+sDot[tid][2]+sDot[tid][3] + attB[l]);
  __syncthreads();
  float sgv[3][4];
  #pragma unroll
  for (int mt=0;mt<3;mt++)
  #pragma unroll
  for (int r=0;r<4;r++)
    sgv[mt][r] = sSig[mt*16 + quad*4 + r];
  #pragma unroll
  for (int nt=0;nt<4;nt++){
    float a = 0.f;
    #pragma unroll
    for (int mt=0;mt<3;mt++)
    #pragma unroll
    for (int r=0;r<4;r++)
      a += acc2[mt][nt][r]*sgv[mt][r];
    a += __shfl_xor(a, 16);
    a += __shfl_xor(a, 32);
    if (quad == 0) agg_bf[(size_t)row*HID + ng*64 + nt*16 + nl] = f2b(a*0.2f);
  }
}

// ---- node MLP + residual + fused QC/QE + fused RC/RE + final outh ----
// grid 256 (1 block/CU), 1024 THREADS = 16 waves = 4 waves/SIMD (TLP 2x
// vs previous; replicates the proven R5 latency-hiding lever). Each wave
// owns ONE 16-column block: n = wv*16 + nl; 3 MFMA streams per wave.
__global__ __launch_bounds__(1024,1) void k_node(
    float* __restrict__ h,
    const u16* __restrict__ agg_bf,
    const u16* __restrict__ W1p, const float* __restrict__ B1,
    const u16* __restrict__ W2p, const float* __restrict__ B2,
    const u16* __restrict__ cWab, u16* __restrict__ QbC, float* __restrict__ RC,
    const u16* __restrict__ eWabN, u16* __restrict__ QbE, float* __restrict__ RE, int doE,
    const u16* __restrict__ WoutP, const float* __restrict__ bout,
    float* __restrict__ outH, int doOut, int l)
{
  __shared__ __align__(16) u16 sA[48*520];
  __shared__ __align__(16) u16 sU[48*264];
  u16* sH = sA;
  int blk=blockIdx.x, tid=threadIdx.x;
  int lane=tid&63, wv=tid>>6, quad=lane>>4, nl=lane&15;
  int base = blk*36;
  // stage h (f32 -> bf16, bit-identical to f2b path) into first 256 cols
  for (int t=tid; t<48*64; t+=1024){
    int i=t>>6, s=t&63;
    unsigned int lo, hi;
    if (i < 36){
      float4 hv = ((const float4*)(h + (size_t)(base+i)*HID))[s];
      lo = (unsigned int)f2b(hv.x) | ((unsigned int)f2b(hv.y) << 16);
      hi = (unsigned int)f2b(hv.z) | ((unsigned int)f2b(hv.w) << 16);
    } else { lo = 0u; hi = 0u; }
    uint2 ov; ov.x = lo; ov.y = hi;
    *(uint2*)(sA + i*520 + s*4) = ov;
  }
  // stage agg (bf16) into cols 256..511; pad rows zero
  for (int t=tid; t<48*32; t+=1024){
    int i=t>>5, q=t&31;
    uint4 v;
    int node = base+i;
    if (i < 36 && node < N_LIGC) v = ((const uint4*)(agg_bf + (size_t)node*HID))[q];
    else { v.x=0u; v.y=0u; v.z=0u; v.w=0u; }
    *(uint4*)(sA + i*520 + 256 + q*8) = v;
  }
  __syncthreads();
  f32x4 zero4 = {0.f,0.f,0.f,0.f};
  int n = wv*16 + nl;   // this wave's output column
  f32x4 acc[3];
  acc[0]=zero4; acc[1]=zero4; acc[2]=zero4;
  const u16* Wp = W1p + (size_t)l*512*HID;
  #pragma unroll 4
  for (int k0=0;k0<16;k0++){
    bf16x8 a0 = *(const bf16x8*)(sA + (0*16+nl)*520 + k0*32 + quad*8);
    bf16x8 a1 = *(const bf16x8*)(sA + (1*16+nl)*520 + k0*32 + quad*8);
    bf16x8 a2 = *(const bf16x8*)(sA + (2*16+nl)*520 + k0*32 + quad*8);
    bf16x8 b0 = *(const bf16x8*)(Wp + ((size_t)(k0*16 + wv)*64 + lane)*8);
    acc[0]=__builtin_amdgcn_mfma_f32_16x16x32_bf16(a0,b0,acc[0],0,0,0);
    acc[1]=__builtin_amdgcn_mfma_f32_16x16x32_bf16(a1,b0,acc[1],0,0,0);
    acc[2]=__builtin_amdgcn_mfma_f32_16x16x32_bf16(a2,b0,acc[2],0,0,0);
  }
  {
    float bb = B1[l*HID + n];
    #pragma unroll
    for (int mt=0;mt<3;mt++)
    #pragma unroll
    for (int r=0;r<4;r++){
      int m = mt*16 + quad*4 + r;
      sU[m*264 + n] = f2b(silu_f(acc[mt][r] + bb));
    }
  }
  __syncthreads();
  f32x4 acc2[3];
  acc2[0]=zero4; acc2[1]=zero4; acc2[2]=zero4;
  const u16* W2 = W2p + (size_t)l*HID*HID;
  #pragma unroll 4
  for (int k0=0;k0<8;k0++){
    bf16x8 a0 = *(const bf16x8*)(sU + (0*16+nl)*264 + k0*32 + quad*8);
    bf16x8 a1 = *(const bf16x8*)(sU + (1*16+nl)*264 + k0*32 + quad*8);
    bf16x8 a2 = *(const bf16x8*)(sU + (2*16+nl)*264 + k0*32 + quad*8);
    bf16x8 b0 = *(const bf16x8*)(W2 + ((size_t)(k0*16 + wv)*64 + lane)*8);
    acc2[0]=__builtin_amdgcn_mfma_f32_16x16x32_bf16(a0,b0,acc2[0],0,0,0);
    acc2[1]=__builtin_amdgcn_mfma_f32_16x16x32_bf16(a1,b0,acc2[1],0,0,0);
    acc2[2]=__builtin_amdgcn_mfma_f32_16x16x32_bf16(a2,b0,acc2[2],0,0,0);
  }
  {
    float bb = B2[l*HID + n];
    #pragma unroll
    for (int mt=0;mt<3;mt++)
    #pragma unroll
    for (int r=0;r<4;r++){
      int m = mt*16 + quad*4 + r;
      if (m < 36){
        size_t idx = (size_t)(base+m)*HID + n;
        float v = h[idx] + acc2[mt][r] + bb;
        h[idx] = v;
        sH[m*264 + n] = f2b(v);
      } else {
        sH[m*264 + n] = 0;
      }
    }
  }
  __syncthreads();

  int isLig = (base < N_LIGC);
  const u16* Wl = cWab + (size_t)l*512*HID;
  // ---- fused QC+QE: one A-pass, dual B ----
  {
    f32x4 qc[3], qe[3];
    qc[0]=zero4; qc[1]=zero4; qc[2]=zero4;
    qe[0]=zero4; qe[1]=zero4; qe[2]=zero4;
    #pragma unroll 4
    for (int k0=0;k0<8;k0++){
      bf16x8 a0 = *(const bf16x8*)(sH + (0*16+nl)*264 + k0*32 + quad*8);
      bf16x8 a1 = *(const bf16x8*)(sH + (1*16+nl)*264 + k0*32 + quad*8);
      bf16x8 a2 = *(const bf16x8*)(sH + (2*16+nl)*264 + k0*32 + quad*8);
      bf16x8 c0 = *(const bf16x8*)(Wl    + ((size_t)((k0+8)*16 + wv)*64 + lane)*8);
      bf16x8 e0 = *(const bf16x8*)(eWabN + ((size_t)((k0+8)*16 + wv)*64 + lane)*8);
      qc[0]=__builtin_amdgcn_mfma_f32_16x16x32_bf16(a0,c0,qc[0],0,0,0);
      qc[1]=__builtin_amdgcn_mfma_f32_16x16x32_bf16(a1,c0,qc[1],0,0,0);
      qc[2]=__builtin_amdgcn_mfma_f32_16x16x32_bf16(a2,c0,qc[2],0,0,0);
      qe[0]=__builtin_amdgcn_mfma_f32_16x16x32_bf16(a0,e0,qe[0],0,0,0);
      qe[1]=__builtin_amdgcn_mfma_f32_16x16x32_bf16(a1,e0,qe[1],0,0,0);
      qe[2]=__builtin_amdgcn_mfma_f32_16x16x32_bf16(a2,e0,qe[2],0,0,0);
    }
    #pragma unroll
    for (int mt=0;mt<3;mt++)
    #pragma unroll
    for (int r=0;r<4;r++){
      int m = mt*16 + quad*4 + r;
      if (m < 36) QbC[(size_t)(base+m)*HID + n] = f2b(qc[mt][r]);
    }
    if (doE){
      #pragma unroll
      for (int mt=0;mt<3;mt++)
      #pragma unroll
      for (int r=0;r<4;r++){
        int m = mt*16 + quad*4 + r;
        if (m < 36) QbE[(size_t)(base+m)*HID + n] = f2b(qe[mt][r]);
      }
    }
  }
  // ---- fused RC+RE (lig blocks only): one A-pass, dual B ----
  if (isLig){
    f32x4 rc[3], re[3];
    rc[0]=zero4; rc[1]=zero4; rc[2]=zero4;
    re[0]=zero4; re[1]=zero4; re[2]=zero4;
    #pragma unroll 4
    for (int k0=0;k0<8;k0++){
      bf16x8 a0 = *(const bf16x8*)(sH + (0*16+nl)*264 + k0*32 + quad*8);
      bf16x8 a1 = *(const bf16x8*)(sH + (1*16+nl)*264 + k0*32 + quad*8);
      bf16x8 a2 = *(const bf16x8*)(sH + (2*16+nl)*264 + k0*32 + quad*8);
      bf16x8 c0 = *(const bf16x8*)(Wl    + ((size_t)(k0*16 + wv)*64 + lane)*8);
      bf16x8 e0 = *(const bf16x8*)(eWabN + ((size_t)(k0*16 + wv)*64 + lane)*8);
      rc[0]=__builtin_amdgcn_mfma_f32_16x16x32_bf16(a0,c0,rc[0],0,0,0);
      rc[1]=__builtin_amdgcn_mfma_f32_16x16x32_bf16(a1,c0,rc[1],0,0,0);
      rc[2]=__builtin_amdgcn_mfma_f32_16x16x32_bf16(a2,c0,rc[2],0,0,0);
      re[0]=__builtin_amdgcn_mfma_f32_16x16x32_bf16(a0,e0,re[0],0,0,0);
      re[1]=__builtin_amdgcn_mfma_f32_16x16x32_bf16(a1,e0,re[1],0,0,0);
      re[2]=__builtin_amdgcn_mfma_f32_16x16x32_bf16(a2,e0,re[2],0,0,0);
    }
    #pragma unroll
    for (int mt=0;mt<3;mt++)
    #pragma unroll
    for (int r=0;r<4;r++){
      int m = mt*16 + quad*4 + r;
      int node = base + m;
      if (m < 36 && node < N_LIGC) RC[(size_t)node*HID + n] = rc[mt][r];
    }
    if (doE){
      #pragma unroll
      for (int mt=0;mt<3;mt++)
      #pragma unroll
      for (int r=0;r<4;r++){
        int m = mt*16 + quad*4 + r;
        int node = base + m;
        if (m < 36 && node < N_LIGC) RE[(size_t)node*HID + n] = re[mt][r];
      }
    }
  }
  if (doOut && isLig && wv < 2){
    int ntw = wv;
    f32x4 o[3]; o[0]=zero4; o[1]=zero4; o[2]=zero4;
    #pragma unroll 2
    for (int k0=0;k0<8;k0++){
      bf16x8 b = *(const bf16x8*)(WoutP + ((size_t)(k0*2 + ntw)*64 + lane)*8);
      #pragma unroll
      for (int mt=0;mt<3;mt++){
        bf16x8 a = *(const bf16x8*)(sH + (mt*16+nl)*264 + k0*32 + quad*8);
        o[mt] = __builtin_amdgcn_mfma_f32_16x16x32_bf16(a,b,o[mt],0,0,0);
      }
    }
    int no = ntw*16 + nl;
    float bb = bout[no];
    #pragma unroll
    for (int mt=0;mt<3;mt++)
    #pragma unroll
    for (int r=0;r<4;r++){
      int m = mt*16 + quad*4 + r;
      int node = base + m;
      if (m < 36 && node < N_LIGC)
        outH[(size_t)node*32 + no] = o[mt][r] + bb;
    }
  }
}

// ---- coord combine (48 edges/block, grid 1024) ----
__global__ __launch_bounds__(256,4) void k_comb_coord(
    const u16* __restrict__ Qb, const float* __restrict__ R,
    const float* __restrict__ xc, float* __restrict__ xn,
    const int* __restrict__ colIdx, const u16* __restrict__ emb0,
    const u16* __restrict__ W1cP, const float* __restrict__ B1,
    const u16* __restrict__ W2p, const float* __restrict__ B2,
    const float* __restrict__ cW3,
    const float* __restrict__ posw, float* __restrict__ outX, int doOut, int l)
{
  __shared__ __align__(16) u16 sQ[48*264];   // Q gather, then M1 in place
  __shared__ __align__(16) u16 sEA[48*40];
  __shared__ float sR[256];
  __shared__ int sCol[48];
  __shared__ float sD[48];
  __shared__ float sCd[48*3];
  __shared__ float sS[48];
  __shared__ float sDot[48][4];

  int row = blockIdx.x, tid = threadIdx.x;
  int lane = tid & 63, ng = tid >> 6;
  int quad = lane >> 4, nl = lane & 15;

  if (tid < 48) sCol[tid] = colIdx[(size_t)row*KNN + tid];
  sR[tid] = R[(size_t)row*HID + tid];
  __syncthreads();
  for (int t = tid; t < 48*32; t += 256){
    int e = t >> 5, q = t & 31;
    uint4 v = ((const uint4*)(Qb + (size_t)sCol[e]*HID))[q];
    *(uint4*)(sQ + e*264 + q*8) = v;
  }
  if (tid < 48){
    int cg = sCol[tid];
    float dx = xc[row*3+0]-xc[cg*3+0];
    float dy = xc[row*3+1]-xc[cg*3+1];
    float dz = xc[row*3+2]-xc[cg*3+2];
    float d = sqrtf(dx*dx+dy*dy+dz*dz + 1e-8f);
    sD[tid] = d;
    float rden = __builtin_amdgcn_rcpf(d + 1.0f);
    sCd[tid*3+0]=dx*rden; sCd[tid*3+1]=dy*rden; sCd[tid*3+2]=dz*rden;
    const unsigned int* ep = (const unsigned int*)(emb0 + ((size_t)row*KNN + tid)*12);
    unsigned int* dd = (unsigned int*)(sEA + tid*40 + 12);
    #pragma unroll
    for (int i=0;i<6;i++) dd[i] = ep[i];
    u16* ea = sEA + tid*40;
    #pragma unroll
    for (int i=24;i<32;i++) ea[i] = 0;
  }
  __syncthreads();
  for (int t=tid; t<288; t+=256){
    int e = t/6, i = t - 6*e;
    float fr = 0.41887903f * (float)(1 << (2*i));
    float x = sD[e]*fr;
    u16* ea = sEA + e*40;
    ea[i]   = f2b(__sinf(x));
    ea[6+i] = f2b(__cosf(x));
  }
  __syncthreads();

  f32x4 zero4 = {0.f,0.f,0.f,0.f};
  f32x4 acc[3][4];
  #pragma unroll
  for (int i=0;i<3;i++){ acc[i][0]=zero4; acc[i][1]=zero4; acc[i][2]=zero4; acc[i][3]=zero4; }
  {
    const u16* Wc = W1cP + (size_t)l*32*HID;
    const u16* wb = Wc + ((size_t)(ng*4)*64 + lane)*8;
    bf16x8 b0 = *(const bf16x8*)(wb);
    bf16x8 b1 = *(const bf16x8*)(wb + 512);
    bf16x8 b2 = *(const bf16x8*)(wb + 1024);
    bf16x8 b3 = *(const bf16x8*)(wb + 1536);
    bf16x8 a0 = *(const bf16x8*)(sEA + (0*16+nl)*40 + quad*8);
    bf16x8 a1 = *(const bf16x8*)(sEA + (1*16+nl)*40 + quad*8);
    bf16x8 a2 = *(const bf16x8*)(sEA + (2*16+nl)*40 + quad*8);
    acc[0][0]=__builtin_amdgcn_mfma_f32_16x16x32_bf16(a0,b0,acc[0][0],0,0,0);
    acc[0][1]=__builtin_amdgcn_mfma_f32_16x16x32_bf16(a0,b1,acc[0][1],0,0,0);
    acc[0][2]=__builtin_amdgcn_mfma_f32_16x16x32_bf16(a0,b2,acc[0][2],0,0,0);
    acc[0][3]=__builtin_amdgcn_mfma_f32_16x16x32_bf16(a0,b3,acc[0][3],0,0,0);
    acc[1][0]=__builtin_amdgcn_mfma_f32_16x16x32_bf16(a1,b0,acc[1][0],0,0,0);
    acc[1][1]=__builtin_amdgcn_mfma_f32_16x16x32_bf16(a1,b1,acc[1][1],0,0,0);
    acc[1][2]=__builtin_amdgcn_mfma_f32_16x16x32_bf16(a1,b2,acc[1][2],0,0,0);
    acc[1][3]=__builtin_amdgcn_mfma_f32_16x16x32_bf16(a1,b3,acc[1][3],0,0,0);
    acc[2][0]=__builtin_amdgcn_mfma_f32_16x16x32_bf16(a2,b0,acc[2][0],0,0,0);
    acc[2][1]=__builtin_amdgcn_mfma_f32_16x16x32_bf16(a2,b1,acc[2][1],0,0,0);
    acc[2][2]=__builtin_amdgcn_mfma_f32_16x16x32_bf16(a2,b2,acc[2][2],0,0,0);
    acc[2][3]=__builtin_amdgcn_mfma_f32_16x16x32_bf16(a2,b3,acc[2][3],0,0,0);
  }
  // in-place M1 epilogue (per-thread RMW ownership; A operand was in sEA)
  #pragma unroll
  for (int mt=0;mt<3;mt++)
  #pragma unroll
  for (int nt=0;nt<4;nt++){
    int n = ng*64 + nt*16 + nl;
    float bb = B1[l*HID + n] + sR[n];
    #pragma unroll
    for (int r=0;r<4;r++){
      int m = mt*16 + quad*4 + r;
      float v = acc[mt][nt][r] + bb + b2f(sQ[m*264 + n]);
      sQ[m*264 + n] = f2b(silu_f(v));
    }
  }
  __syncthreads();

  f32x4 acc2[3][4];
  #pragma unroll
  for (int i=0;i<3;i++){ acc2[i][0]=zero4; acc2[i][1]=zero4; acc2[i][2]=zero4; acc2[i][3]=zero4; }
  const u16* W2 = W2p + (size_t)l*HID*HID;
  #pragma unroll 2
  for (int k0=0;k0<8;k0++){
    bf16x8 a0 = *(const bf16x8*)(sQ + (0*16+nl)*264 + k0*32 + quad*8);
    bf16x8 a1 = *(const bf16x8*)(sQ + (1*16+nl)*264 + k0*32 + quad*8);
    bf16x8 a2 = *(const bf16x8*)(sQ + (2*16+nl)*264 + k0*32 + quad*8);
    const u16* wb = W2 + ((size_t)(k0*16 + ng*4)*64 + lane)*8;
    bf16x8 b0 = *(const bf16x8*)(wb);
    bf16x8 b1 = *(const bf16x8*)(wb + 512);
    bf16x8 b2 = *(const bf16x8*)(wb + 1024);
    bf16x8 b3 = *(const bf16x8*)(wb + 1536);
    acc2[0][0]=__builtin_amdgcn_mfma_f32_16x16x32_bf16(a0,b0,acc2[0][0],0,0,0);
    acc2[0][1]=__builtin_amdgcn_mfma_f32_16x16x32_bf16(a0,b1,acc2[0][1],0,0,0);
    acc2[0][2]=__builtin_amdgcn_mfma_f32_16x16x32_bf16(a0,b2,acc2[0][2],0,0,0);
    acc2[0][3]=__builtin_amdgcn_mfma_f32_16x16x32_bf16(a0,b3,acc2[0][3],0,0,0);
    acc2[1][0]=__builtin_amdgcn_mfma_f32_16x16x32_bf16(a1,b0,acc2[1][0],0,0,0);
    acc2[1][1]=__builtin_amdgcn_mfma_f32_16x16x32_bf16(a1,b1,acc2[1][1],0,0,0);
    acc2[1][2]=__builtin_amdgcn_mfma_f32_16x16x32_bf16(a1,b2,acc2[1][2],0,0,0);
    acc2[1][3]=__builtin_amdgcn_mfma_f32_16x16x32_bf16(a1,b3,acc2[1][3],0,0,0);
    acc2[2][0]=__builtin_amdgcn_mfma_f32_16x16x32_bf16(a2,b0,acc2[2][0],0,0,0);
    acc2[2][1]=__builtin_amdgcn_mfma_f32_16x16x32_bf16(a2,b1,acc2[2][1],0,0,0);
    acc2[2][2]=__builtin_amdgcn_mfma_f32_16x16x32_bf16(a2,b2,acc2[2][2],0,0,0);
    acc2[2][3]=__builtin_amdgcn_mfma_f32_16x16x32_bf16(a2,b3,acc2[2][3],0,0,0);
  }
  // register epilogue: silu + dot with cW3, shfl-reduce over nl
  float cw[4], bb2[4];
  #pragma unroll
  for (int nt=0;nt<4;nt++){
    int n = ng*64 + nt*16 + nl;
    cw[nt]  = cW3[l*HID + n];
    bb2[nt] = B2[l*HID + n];
  }
  float dotp[3][4];
  #pragma unroll
  for (int mt=0;mt<3;mt++){
    #pragma unroll
    for (int r=0;r<4;r++) dotp[mt][r] = 0.f;
    #pragma unroll
    for (int nt=0;nt<4;nt++){
      #pragma unroll
      for (int r=0;r<4;r++){
        float s = silu_f(acc2[mt][nt][r] + bb2[nt]);
        dotp[mt][r] += s*cw[nt];
      }
    }
  }
  #pragma unroll
  for (int off=1; off<16; off<<=1){
    #pragma unroll
    for (int mt=0;mt<3;mt++)
    #pragma unroll
    for (int r=0;r<4;r++)
      dotp[mt][r] += __shfl_xor(dotp[mt][r], off);
  }
  if (nl == 0){
    #pragma unroll
    for (int mt=0;mt<3;mt++)
    #pragma unroll
    for (int r=0;r<4;r++)
      sDot[mt*16 + quad*4 + r][ng] = dotp[mt][r];
  }
  __syncthreads();
  if (tid < 48) sS[tid] = sDot[tid][0]+sDot[tid][1]+sDot[tid][2]+sDot[tid][3];
  __syncthreads();
  if (tid < 3){
    float u = 0.f;
    #pragma unroll 4
    for (int e=0;e<48;e++) u += sCd[e*3+tid]*sS[e];
    float nv = xc[row*3+tid] + u*0.2f;
    xn[row*3+tid] = nv;
    if (doOut) outX[row*3+tid] = nv*posw[0];
  }
}

extern "C" void kernel_launch(void* const* d_in, const int* in_sizes, int n_in,
                              void* d_out, int out_size, void* d_ws, size_t ws_size,
                              hipStream_t stream)
{
  const float* protPos = (const float*)d_in[0];
  const int*   protEle = (const int*)d_in[1];
  const int*   protAA  = (const int*)d_in[2];
  const int*   protBB  = (const int*)d_in[3];
  const float* XtPos   = (const float*)d_in[4];
  const float* XtFeat  = (const float*)d_in[5];
  const int*   tArr    = (const int*)d_in[6];
  const float* WtTime  = (const float*)d_in[7];
  const float* Wele    = (const float*)d_in[8];
  const float* Waa     = (const float*)d_in[9];
  const float* Wbb     = (const float*)d_in[10];
  const float* Win     = (const float*)d_in[11];
  const float* bin     = (const float*)d_in[12];
  const float* Wout    = (const float*)d_in[13];
  const float* bout    = (const float*)d_in[14];
  const float* eW1     = (const float*)d_in[15];
  const float* eB1     = (const float*)d_in[16];
  const float* eW2     = (const float*)d_in[17];
  const float* eB2     = (const float*)d_in[18];
  const float* attW    = (const float*)d_in[19];
  const float* attB    = (const float*)d_in[20];
  const float* nW1     = (const float*)d_in[21];
  const float* nB1     = (const float*)d_in[22];
  const float* nW2     = (const float*)d_in[23];
  const float* nB2     = (const float*)d_in[24];
  const float* cW1     = (const float*)d_in[25];
  const float* cB1     = (const float*)d_in[26];
  const float* cW2     = (const float*)d_in[27];
  const float* cB2     = (const float*)d_in[28];
  const float* cW3     = (const float*)d_in[29];
  const float* posw    = (const float*)d_in[30];

  float* fp = (float*)d_ws;
  float* X0   = fp;               fp += NTOT*3;
  float* X1   = fp;               fp += NTOT*3;
  float* h    = fp;               fp += (size_t)NTOT*HID;
  float* RC   = fp;               fp += (size_t)N_LIGC*HID;
  float* RE   = fp;               fp += (size_t)N_LIGC*HID;
  int*   col  = (int*)fp;         fp += ETOT;
  u16*   up   = (u16*)fp;
  u16* emb0   = up;               up += (size_t)ETOT*12;
  u16* h_bf   = up;               up += (size_t)NTOT*HID;
  u16* agg_bf = up;               up += (size_t)N_LIGC*HID;
  u16* QbE    = up;               up += (size_t)NTOT*HID;
  u16* QbC    = up;               up += (size_t)NTOT*HID;
  u16* eW1abP = up;               up += (size_t)DEPTHC*512*HID;
  u16* eW1cP  = up;               up += (size_t)DEPTHC*32*HID;
  u16* eW2p   = up;               up += (size_t)DEPTHC*HID*HID;
  u16* nW1p   = up;               up += (size_t)DEPTHC*512*HID;
  u16* nW2p   = up;               up += (size_t)DEPTHC*HID*HID;
  u16* cW1abP = up;               up += (size_t)DEPTHC*512*HID;
  u16* cW1cP  = up;               up += (size_t)DEPTHC*32*HID;
  u16* cW2p   = up;               up += (size_t)DEPTHC*HID*HID;
  u16* WoutP  = up;               up += (size_t)256*32;

  k_prep<<<PACK_BLKS + NTOT/8,256,0,stream>>>(eW1,eW2,nW1,nW2,cW1,cW2,Wout,
      eW1abP,eW1cP,eW2p,nW1p,nW2p,cW1abP,cW1cP,cW2p,WoutP,
      protPos,protEle,protAA,protBB,XtPos,XtFeat,
      tArr,WtTime,Wele,Waa,Wbb,Win,bin,X0,X1,h,h_bf);
  k_knn_pq<<<256 + N_LIGC,512,0,stream>>>(X0,col,emb0,h_bf,eW1abP,RE,QbE);

  float* xc = X0; float* xn = X1;
  float* outF = (float*)d_out;
  for (int l=0;l<DEPTHC;l++){
    k_comb_edge<<<N_LIGC,256,0,stream>>>(QbE,RE,xc,col,emb0,eW1cP,eB1,eW2p,eB2,attW,attB,agg_bf,l);
    const u16* eNext = eW1abP + (size_t)((l+1)%DEPTHC)*512*HID;
    k_node<<<256,1024,0,stream>>>(h,agg_bf,nW1p,nB1,nW2p,nB2,
        cW1abP,QbC,RC, eNext,QbE,RE,(l<DEPTHC-1)?1:0,
        WoutP,bout, outF+3072, (l==DEPTHC-1)?1:0, l);
    k_comb_coord<<<N_LIGC,256,0,stream>>>(QbC,RC,xc,xn,col,emb0,cW1cP,cB1,cW2p,cB2,cW3,
        posw, outF, (l==DEPTHC-1)?1:0, l);
    float* t2=xc; xc=xn; xn=t2;
  }
}